// Round 5
// baseline (595.221 us; speedup 1.0000x reference)
//
#include <hip/hip_runtime.h>

// GraphSAGE 3-layer (mean agg), N=100000, E=1600000, 128->32->32->16.
// Round 5: (a) two-phase bucketed CSR fill — round 4's direct fill wrote 107 MB
// HBM (16x write-amp from 4B random scatter); bucketing to 64-node dst-windows
// keeps scatter radius ~8KB so L2 merges lines. (b) wave-per-node gather
// (64/D neighbors in parallel + unroll 2) to double memory parallelism.

#define BLOCK 256
#define BSHIFT 6          // 64 nodes per bucket

// ---------------- degree (int atomics) ----------------
__global__ void degree_kernel(const int* __restrict__ dst, int* __restrict__ deg, int n_edges) {
    int e = blockIdx.x * blockDim.x + threadIdx.x;
    if (e < n_edges) atomicAdd(&deg[dst[e]], 1);
}

// ---------------- scan phase A: per-block sums of deg ----------------
__global__ void scanA_kernel(const int* __restrict__ deg, int* __restrict__ bsum, int n_nodes) {
    int i = blockIdx.x * blockDim.x + threadIdx.x;
    int d = (i < n_nodes) ? deg[i] : 0;
    int v = d;
    for (int off = 32; off > 0; off >>= 1) v += __shfl_down(v, off);
    __shared__ int wsum[BLOCK / 64];
    int lane = threadIdx.x & 63, wv = threadIdx.x >> 6;
    if (lane == 0) wsum[wv] = v;
    __syncthreads();
    if (threadIdx.x == 0) {
        int s = 0;
        for (int w = 0; w < BLOCK / 64; ++w) s += wsum[w];
        bsum[blockIdx.x] = s;
    }
}

// ---------------- scan phase B: exclusive scan of block sums ----------------
__global__ void scanB_kernel(int* __restrict__ bsum, int* __restrict__ boff,
                             int* __restrict__ start_last, int nblocks) {
    __shared__ int sh[1024];
    int tid = threadIdx.x;
    sh[tid] = (tid < nblocks) ? bsum[tid] : 0;
    __syncthreads();
    for (int off = 1; off < 1024; off <<= 1) {
        int v = (tid >= off) ? sh[tid - off] : 0;
        __syncthreads();
        sh[tid] += v;
        __syncthreads();
    }
    if (tid < nblocks) boff[tid] = sh[tid] - bsum[tid];
    if (tid == 1023) *start_last = sh[1023];
}

// ---------------- scan phase C: excl scan + invdeg + cursor=0 + bucket bases ----------------
__global__ void scanC_kernel(const int* __restrict__ deg, const int* __restrict__ boff,
                             int* __restrict__ start, float* __restrict__ invdeg,
                             int* __restrict__ cursor, int* __restrict__ bcur, int n_nodes) {
    int tid = threadIdx.x;
    int i = blockIdx.x * blockDim.x + tid;
    int d = (i < n_nodes) ? deg[i] : 0;
    int lane = tid & 63, wv = tid >> 6;
    int v = d;
    for (int off = 1; off < 64; off <<= 1) {
        int u = __shfl_up(v, off);
        if (lane >= off) v += u;
    }
    __shared__ int wsum[BLOCK / 64];
    if (lane == 63) wsum[wv] = v;
    __syncthreads();
    int wadd = 0;
    for (int w = 0; w < wv; ++w) wadd += wsum[w];
    int excl = v - d + wadd + boff[blockIdx.x];
    if (i < n_nodes) {
        start[i] = excl;
        invdeg[i] = 1.0f / (float)(d < 1 ? 1 : d);
        cursor[i] = 0;
        if ((i & ((1 << BSHIFT) - 1)) == 0) bcur[i >> BSHIFT] = excl;  // bucket base
    }
}

// ---------------- fill phase 1: scatter (src,dst) pairs into dst-buckets ----------------
__global__ void fill_bucket(const int* __restrict__ src, const int* __restrict__ dst,
                            int* __restrict__ bcur, int2* __restrict__ pairs, int n_edges) {
    int e = blockIdx.x * blockDim.x + threadIdx.x;
    if (e >= n_edges) return;
    int s = src[e];
    int d = dst[e];
    int slot = atomicAdd(&bcur[d >> BSHIFT], 1);
    pairs[slot] = make_int2(s, d);
}

// ---------------- fill phase 2: bucket-local scatter into final CSR ----------------
__global__ void fill_csr(const int2* __restrict__ pairs, const int* __restrict__ start,
                         int* __restrict__ cursor, int* __restrict__ csr_src, int n_edges) {
    int e = blockIdx.x * blockDim.x + threadIdx.x;
    if (e >= n_edges) return;
    int2 pr = pairs[e];
    int slot = start[pr.y] + atomicAdd(&cursor[pr.y], 1);
    csr_src[slot] = pr.x;
}

// ---------------- register-tiled projection: pre = h@Ws + b ; p = h@Wn ----------------
template<int DIN, int DOUT>
__global__ __launch_bounds__(256, 2)
void proj_tiled(const float* __restrict__ h,
                const float* __restrict__ Ws,
                const float* __restrict__ Wn,
                const float* __restrict__ bias,
                float* __restrict__ pre,
                float* __restrict__ p,
                int n_nodes) {
    constexpr int OD  = 2 * DOUT;
    constexpr int OPT = 8;
    constexpr int OG  = OD / OPT;
    constexpr int NPT = 4;
    constexpr int NG  = 256 / OG;
    constexpr int NT  = NPT * NG;
    constexpr int KC  = 32;
    constexpr int NCH = DIN / KC;

    __shared__ float sW[DIN][OD];
    __shared__ float sx[NT][KC + 1];
    __shared__ float sb[DOUT];

    const int tid = threadIdx.x;
    for (int i = tid; i < DIN * OD; i += 256) {
        int k = i / OD, o = i % OD;
        sW[k][o] = (o < DOUT) ? Ws[k * DOUT + o] : Wn[k * DOUT + (o - DOUT)];
    }
    if (tid < DOUT) sb[tid] = bias[tid];

    const int to = tid % OG;
    const int tn = tid / OG;
    const int o0 = to * OPT;
    const int node0 = blockIdx.x * NT;

    float acc[NPT][OPT];
#pragma unroll
    for (int n = 0; n < NPT; ++n)
#pragma unroll
        for (int o = 0; o < OPT; ++o) acc[n][o] = 0.f;

    constexpr int L4 = NT * KC / (256 * 4);
    for (int c = 0; c < NCH; ++c) {
        if (c > 0) __syncthreads();
#pragma unroll
        for (int q = 0; q < L4; ++q) {
            int fq   = q * 256 + tid;
            int node = fq / (KC / 4);
            int kq   = fq % (KC / 4);
            float4 v = make_float4(0.f, 0.f, 0.f, 0.f);
            int gn = node0 + node;
            if (gn < n_nodes)
                v = *reinterpret_cast<const float4*>(h + (size_t)gn * DIN + c * KC + kq * 4);
            sx[node][kq * 4 + 0] = v.x;
            sx[node][kq * 4 + 1] = v.y;
            sx[node][kq * 4 + 2] = v.z;
            sx[node][kq * 4 + 3] = v.w;
        }
        __syncthreads();

#pragma unroll 8
        for (int k = 0; k < KC; ++k) {
            const float4 wa = *reinterpret_cast<const float4*>(&sW[c * KC + k][o0]);
            const float4 wb = *reinterpret_cast<const float4*>(&sW[c * KC + k][o0 + 4]);
            float xv[NPT];
#pragma unroll
            for (int n = 0; n < NPT; ++n) xv[n] = sx[tn * NPT + n][k];
#pragma unroll
            for (int n = 0; n < NPT; ++n) {
                acc[n][0] = fmaf(xv[n], wa.x, acc[n][0]);
                acc[n][1] = fmaf(xv[n], wa.y, acc[n][1]);
                acc[n][2] = fmaf(xv[n], wa.z, acc[n][2]);
                acc[n][3] = fmaf(xv[n], wa.w, acc[n][3]);
                acc[n][4] = fmaf(xv[n], wb.x, acc[n][4]);
                acc[n][5] = fmaf(xv[n], wb.y, acc[n][5]);
                acc[n][6] = fmaf(xv[n], wb.z, acc[n][6]);
                acc[n][7] = fmaf(xv[n], wb.w, acc[n][7]);
            }
        }
    }

    const bool self_half = (o0 < DOUT);
#pragma unroll
    for (int n = 0; n < NPT; ++n) {
        int node = node0 + tn * NPT + n;
        if (node >= n_nodes) continue;
        if (self_half) {
            float4 r0 = make_float4(acc[n][0] + sb[o0 + 0], acc[n][1] + sb[o0 + 1],
                                    acc[n][2] + sb[o0 + 2], acc[n][3] + sb[o0 + 3]);
            float4 r1 = make_float4(acc[n][4] + sb[o0 + 4], acc[n][5] + sb[o0 + 5],
                                    acc[n][6] + sb[o0 + 6], acc[n][7] + sb[o0 + 7]);
            *reinterpret_cast<float4*>(pre + (size_t)node * DOUT + o0)     = r0;
            *reinterpret_cast<float4*>(pre + (size_t)node * DOUT + o0 + 4) = r1;
        } else {
            int oo = o0 - DOUT;
            float4 r0 = make_float4(acc[n][0], acc[n][1], acc[n][2], acc[n][3]);
            float4 r1 = make_float4(acc[n][4], acc[n][5], acc[n][6], acc[n][7]);
            *reinterpret_cast<float4*>(p + (size_t)node * DOUT + oo)     = r0;
            *reinterpret_cast<float4*>(p + (size_t)node * DOUT + oo + 4) = r1;
        }
    }
}

// ---------------- wave-per-node gather + finalize ----------------
// 64-lane wave = (64/D) neighbor sub-groups x D features; unroll 2.
template<int D, bool RELU>
__global__ void gather_kernel(const float* __restrict__ p,
                              const int* __restrict__ csr_src,
                              const int* __restrict__ start,
                              const float* __restrict__ pre,
                              const float* __restrict__ invdeg,
                              float* __restrict__ out,
                              int n_nodes) {
    constexpr int NPG = 64 / D;             // neighbors per wave-iteration
    int wave = threadIdx.x >> 6;
    int lane = threadIdx.x & 63;
    int g = blockIdx.x * (blockDim.x >> 6) + wave;
    if (g >= n_nodes) return;
    int sub = lane / D;
    int f   = lane % D;
    int s0 = start[g];
    int s1 = start[g + 1];
    float a0 = 0.f, a1 = 0.f;
    int j = s0 + sub;
    for (; j + NPG < s1; j += 2 * NPG) {
        int c0 = csr_src[j];
        int c1 = csr_src[j + NPG];
        a0 += p[c0 * D + f];
        a1 += p[c1 * D + f];
    }
    if (j < s1) a0 += p[csr_src[j] * D + f];
    float a = a0 + a1;
    // reduce across neighbor sub-groups (lane strides of D)
    a += __shfl_down(a, 32);
    if (D == 16) a += __shfl_down(a, 16);
    if (lane < D) {
        int o = g * D + f;
        float v = pre[o] + a * invdeg[g];
        if (RELU) v = fmaxf(v, 0.f);
        out[o] = v;
    }
}

extern "C" void kernel_launch(void* const* d_in, const int* in_sizes, int n_in,
                              void* d_out, int out_size, void* d_ws, size_t ws_size,
                              hipStream_t stream) {
    const float* x        = (const float*)d_in[0];
    const int*   edge_src = (const int*)d_in[1];
    const int*   edge_dst = (const int*)d_in[2];
    const float* Ws1 = (const float*)d_in[3];
    const float* Wn1 = (const float*)d_in[4];
    const float* b1  = (const float*)d_in[5];
    const float* Ws2 = (const float*)d_in[6];
    const float* Wn2 = (const float*)d_in[7];
    const float* b2  = (const float*)d_in[8];
    const float* Ws3 = (const float*)d_in[9];
    const float* Wn3 = (const float*)d_in[10];
    const float* b3  = (const float*)d_in[11];
    float* out = (float*)d_out;

    const int IN = 128, HID = 32;
    const int n_nodes = in_sizes[0] / IN;
    const int n_edges = in_sizes[1];

    char* wsb = (char*)d_ws;
    size_t off = 0;
    auto alloc = [&](size_t bytes) { char* r = wsb + off; off = (off + bytes + 255) & ~(size_t)255; return r; };
    int*   deg    = (int*)alloc((size_t)n_nodes * sizeof(int));
    int*   cursor = (int*)alloc((size_t)n_nodes * sizeof(int));
    int*   startp = (int*)alloc(((size_t)n_nodes + 1) * sizeof(int));
    float* invdeg = (float*)alloc((size_t)n_nodes * sizeof(float));
    int*   csr    = (int*)alloc((size_t)n_edges * sizeof(int));
    int*   bsum   = (int*)alloc(1024 * sizeof(int));
    int*   boff   = (int*)alloc(1024 * sizeof(int));
    int*   bcur   = (int*)alloc(4096 * sizeof(int));
    float* B0     = (float*)alloc((size_t)n_nodes * HID * sizeof(float));  // pre
    float* B1     = (float*)alloc((size_t)n_nodes * HID * sizeof(float));  // p
    float* B3     = (float*)alloc((size_t)n_nodes * HID * sizeof(float));  // h
    // pairs buffer aliases B0+B1 region is NOT safe (B1 written by proj1 too) —
    // but CSR build fully precedes proj1 on the stream, so aliasing B0 is safe:
    int2*  pairs  = (int2*)B0;   // needs n_edges*8 = 12.8MB; B0 = 12.8MB exactly

    const int gEdges = (n_edges + BLOCK - 1) / BLOCK;
    const int gNodes = (n_nodes + BLOCK - 1) / BLOCK;
    const int gP12   = (n_nodes + 127) / 128;
    const int gP3    = (n_nodes + 255) / 256;
    const int gGat   = (n_nodes + 3) / 4;      // 4 waves per block = 4 nodes

    // ---- CSR build ----
    hipMemsetAsync(deg, 0, (size_t)n_nodes * sizeof(int), stream);
    degree_kernel<<<gEdges, BLOCK, 0, stream>>>(edge_dst, deg, n_edges);
    scanA_kernel<<<gNodes, BLOCK, 0, stream>>>(deg, bsum, n_nodes);
    scanB_kernel<<<1, 1024, 0, stream>>>(bsum, boff, startp + n_nodes, gNodes);
    scanC_kernel<<<gNodes, BLOCK, 0, stream>>>(deg, boff, startp, invdeg, cursor, bcur, n_nodes);
    fill_bucket<<<gEdges, BLOCK, 0, stream>>>(edge_src, edge_dst, bcur, pairs, n_edges);
    fill_csr<<<gEdges, BLOCK, 0, stream>>>(pairs, startp, cursor, csr, n_edges);

    // ---- layer 1: 128 -> 32, relu ----
    proj_tiled<128, 32><<<gP12, BLOCK, 0, stream>>>(x, Ws1, Wn1, b1, B0, B1, n_nodes);
    gather_kernel<32, true><<<gGat, BLOCK, 0, stream>>>(B1, csr, startp, B0, invdeg, B3, n_nodes);

    // ---- layer 2: 32 -> 32, relu ----
    proj_tiled<32, 32><<<gP12, BLOCK, 0, stream>>>(B3, Ws2, Wn2, b2, B0, B1, n_nodes);
    gather_kernel<32, true><<<gGat, BLOCK, 0, stream>>>(B1, csr, startp, B0, invdeg, B3, n_nodes);

    // ---- layer 3: 32 -> 16, no relu ----
    proj_tiled<32, 16><<<gP3, BLOCK, 0, stream>>>(B3, Ws3, Wn3, b3, B0, B1, n_nodes);
    gather_kernel<16, false><<<gGat, BLOCK, 0, stream>>>(B1, csr, startp, B0, invdeg, out, n_nodes);
}

// Round 6
// 380.548 us; speedup vs baseline: 1.5641x; 1.5641x over previous
//
#include <hip/hip_runtime.h>

// GraphSAGE 3-layer (mean agg), N=100000, E=1600000, 128->32->32->16.
// Round 6: direct CSR fill with dst-windowed passes + XCD affinity.
// Round 5's bucket counters (1563 hot atomics-with-return) serialized (239us);
// round 4's direct fill had 16x write-amp (107MB). Here: window = blockIdx&7
// (round-robin XCD dispatch) so each ~800KB CSR window is written by ONE XCD's
// L2 -> lines fill before writeback; dst/src re-reads come from the shared L3.

#define BLOCK 256
#define NWIN 8
#define FILL_CHUNK 4096

// ---------------- degree (int atomics) ----------------
__global__ void degree_kernel(const int* __restrict__ dst, int* __restrict__ deg, int n_edges) {
    int e = blockIdx.x * blockDim.x + threadIdx.x;
    if (e < n_edges) atomicAdd(&deg[dst[e]], 1);
}

// ---------------- scan phase A: per-block sums of deg ----------------
__global__ void scanA_kernel(const int* __restrict__ deg, int* __restrict__ bsum, int n_nodes) {
    int i = blockIdx.x * blockDim.x + threadIdx.x;
    int d = (i < n_nodes) ? deg[i] : 0;
    int v = d;
    for (int off = 32; off > 0; off >>= 1) v += __shfl_down(v, off);
    __shared__ int wsum[BLOCK / 64];
    int lane = threadIdx.x & 63, wv = threadIdx.x >> 6;
    if (lane == 0) wsum[wv] = v;
    __syncthreads();
    if (threadIdx.x == 0) {
        int s = 0;
        for (int w = 0; w < BLOCK / 64; ++w) s += wsum[w];
        bsum[blockIdx.x] = s;
    }
}

// ---------------- scan phase B: exclusive scan of block sums ----------------
__global__ void scanB_kernel(int* __restrict__ bsum, int* __restrict__ boff,
                             int* __restrict__ start_last, int nblocks) {
    __shared__ int sh[1024];
    int tid = threadIdx.x;
    sh[tid] = (tid < nblocks) ? bsum[tid] : 0;
    __syncthreads();
    for (int off = 1; off < 1024; off <<= 1) {
        int v = (tid >= off) ? sh[tid - off] : 0;
        __syncthreads();
        sh[tid] += v;
        __syncthreads();
    }
    if (tid < nblocks) boff[tid] = sh[tid] - bsum[tid];
    if (tid == 1023) *start_last = sh[1023];
}

// ---------------- scan phase C: excl scan + invdeg + cursor=0 ----------------
__global__ void scanC_kernel(const int* __restrict__ deg, const int* __restrict__ boff,
                             int* __restrict__ start, float* __restrict__ invdeg,
                             int* __restrict__ cursor, int n_nodes) {
    int tid = threadIdx.x;
    int i = blockIdx.x * blockDim.x + tid;
    int d = (i < n_nodes) ? deg[i] : 0;
    int lane = tid & 63, wv = tid >> 6;
    int v = d;
    for (int off = 1; off < 64; off <<= 1) {
        int u = __shfl_up(v, off);
        if (lane >= off) v += u;
    }
    __shared__ int wsum[BLOCK / 64];
    if (lane == 63) wsum[wv] = v;
    __syncthreads();
    int wadd = 0;
    for (int w = 0; w < wv; ++w) wadd += wsum[w];
    int excl = v - d + wadd + boff[blockIdx.x];
    if (i < n_nodes) {
        start[i] = excl;
        invdeg[i] = 1.0f / (float)(d < 1 ? 1 : d);
        cursor[i] = 0;
    }
}

// ---------------- CSR fill: dst-windowed, XCD-affine ----------------
// blockIdx&7 selects a 1/8 dst-window; consecutive blocks round-robin XCDs,
// so each window's ~800KB output region is owned by one XCD's L2.
__global__ void fill_win(const int* __restrict__ src, const int* __restrict__ dst,
                         const int* __restrict__ start, int* __restrict__ cursor,
                         int* __restrict__ csr_src, int n_edges, int wnodes) {
    int wi = blockIdx.x & (NWIN - 1);
    int c  = blockIdx.x >> 3;
    int lo = wi * wnodes, hi = lo + wnodes;
    int e0 = c * FILL_CHUNK;
    int e1 = e0 + FILL_CHUNK; if (e1 > n_edges) e1 = n_edges;
    for (int e = e0 + threadIdx.x; e < e1; e += BLOCK) {
        int d = dst[e];
        if (d >= lo && d < hi) {
            int slot = start[d] + atomicAdd(&cursor[d], 1);
            csr_src[slot] = src[e];
        }
    }
}

// ---------------- register-tiled projection: pre = h@Ws + b ; p = h@Wn ----------------
template<int DIN, int DOUT>
__global__ __launch_bounds__(256, 2)
void proj_tiled(const float* __restrict__ h,
                const float* __restrict__ Ws,
                const float* __restrict__ Wn,
                const float* __restrict__ bias,
                float* __restrict__ pre,
                float* __restrict__ p,
                int n_nodes) {
    constexpr int OD  = 2 * DOUT;
    constexpr int OPT = 8;
    constexpr int OG  = OD / OPT;
    constexpr int NPT = 4;
    constexpr int NG  = 256 / OG;
    constexpr int NT  = NPT * NG;
    constexpr int KC  = 32;
    constexpr int NCH = DIN / KC;

    __shared__ float sW[DIN][OD];
    __shared__ float sx[NT][KC + 1];
    __shared__ float sb[DOUT];

    const int tid = threadIdx.x;
    for (int i = tid; i < DIN * OD; i += 256) {
        int k = i / OD, o = i % OD;
        sW[k][o] = (o < DOUT) ? Ws[k * DOUT + o] : Wn[k * DOUT + (o - DOUT)];
    }
    if (tid < DOUT) sb[tid] = bias[tid];

    const int to = tid % OG;
    const int tn = tid / OG;
    const int o0 = to * OPT;
    const int node0 = blockIdx.x * NT;

    float acc[NPT][OPT];
#pragma unroll
    for (int n = 0; n < NPT; ++n)
#pragma unroll
        for (int o = 0; o < OPT; ++o) acc[n][o] = 0.f;

    constexpr int L4 = NT * KC / (256 * 4);
    for (int c = 0; c < NCH; ++c) {
        if (c > 0) __syncthreads();
#pragma unroll
        for (int q = 0; q < L4; ++q) {
            int fq   = q * 256 + tid;
            int node = fq / (KC / 4);
            int kq   = fq % (KC / 4);
            float4 v = make_float4(0.f, 0.f, 0.f, 0.f);
            int gn = node0 + node;
            if (gn < n_nodes)
                v = *reinterpret_cast<const float4*>(h + (size_t)gn * DIN + c * KC + kq * 4);
            sx[node][kq * 4 + 0] = v.x;
            sx[node][kq * 4 + 1] = v.y;
            sx[node][kq * 4 + 2] = v.z;
            sx[node][kq * 4 + 3] = v.w;
        }
        __syncthreads();

#pragma unroll 8
        for (int k = 0; k < KC; ++k) {
            const float4 wa = *reinterpret_cast<const float4*>(&sW[c * KC + k][o0]);
            const float4 wb = *reinterpret_cast<const float4*>(&sW[c * KC + k][o0 + 4]);
            float xv[NPT];
#pragma unroll
            for (int n = 0; n < NPT; ++n) xv[n] = sx[tn * NPT + n][k];
#pragma unroll
            for (int n = 0; n < NPT; ++n) {
                acc[n][0] = fmaf(xv[n], wa.x, acc[n][0]);
                acc[n][1] = fmaf(xv[n], wa.y, acc[n][1]);
                acc[n][2] = fmaf(xv[n], wa.z, acc[n][2]);
                acc[n][3] = fmaf(xv[n], wa.w, acc[n][3]);
                acc[n][4] = fmaf(xv[n], wb.x, acc[n][4]);
                acc[n][5] = fmaf(xv[n], wb.y, acc[n][5]);
                acc[n][6] = fmaf(xv[n], wb.z, acc[n][6]);
                acc[n][7] = fmaf(xv[n], wb.w, acc[n][7]);
            }
        }
    }

    const bool self_half = (o0 < DOUT);
#pragma unroll
    for (int n = 0; n < NPT; ++n) {
        int node = node0 + tn * NPT + n;
        if (node >= n_nodes) continue;
        if (self_half) {
            float4 r0 = make_float4(acc[n][0] + sb[o0 + 0], acc[n][1] + sb[o0 + 1],
                                    acc[n][2] + sb[o0 + 2], acc[n][3] + sb[o0 + 3]);
            float4 r1 = make_float4(acc[n][4] + sb[o0 + 4], acc[n][5] + sb[o0 + 5],
                                    acc[n][6] + sb[o0 + 6], acc[n][7] + sb[o0 + 7]);
            *reinterpret_cast<float4*>(pre + (size_t)node * DOUT + o0)     = r0;
            *reinterpret_cast<float4*>(pre + (size_t)node * DOUT + o0 + 4) = r1;
        } else {
            int oo = o0 - DOUT;
            float4 r0 = make_float4(acc[n][0], acc[n][1], acc[n][2], acc[n][3]);
            float4 r1 = make_float4(acc[n][4], acc[n][5], acc[n][6], acc[n][7]);
            *reinterpret_cast<float4*>(p + (size_t)node * DOUT + oo)     = r0;
            *reinterpret_cast<float4*>(p + (size_t)node * DOUT + oo + 4) = r1;
        }
    }
}

// ---------------- wave-per-node gather + finalize ----------------
template<int D, bool RELU>
__global__ void gather_kernel(const float* __restrict__ p,
                              const int* __restrict__ csr_src,
                              const int* __restrict__ start,
                              const float* __restrict__ pre,
                              const float* __restrict__ invdeg,
                              float* __restrict__ out,
                              int n_nodes) {
    constexpr int NPG = 64 / D;
    int wave = threadIdx.x >> 6;
    int lane = threadIdx.x & 63;
    int g = blockIdx.x * (blockDim.x >> 6) + wave;
    if (g >= n_nodes) return;
    int sub = lane / D;
    int f   = lane % D;
    int s0 = start[g];
    int s1 = start[g + 1];
    float a0 = 0.f, a1 = 0.f;
    int j = s0 + sub;
    for (; j + NPG < s1; j += 2 * NPG) {
        int c0 = csr_src[j];
        int c1 = csr_src[j + NPG];
        a0 += p[c0 * D + f];
        a1 += p[c1 * D + f];
    }
    if (j < s1) a0 += p[csr_src[j] * D + f];
    float a = a0 + a1;
    a += __shfl_down(a, 32);
    if (D == 16) a += __shfl_down(a, 16);
    if (lane < D) {
        int o = g * D + f;
        float v = pre[o] + a * invdeg[g];
        if (RELU) v = fmaxf(v, 0.f);
        out[o] = v;
    }
}

extern "C" void kernel_launch(void* const* d_in, const int* in_sizes, int n_in,
                              void* d_out, int out_size, void* d_ws, size_t ws_size,
                              hipStream_t stream) {
    const float* x        = (const float*)d_in[0];
    const int*   edge_src = (const int*)d_in[1];
    const int*   edge_dst = (const int*)d_in[2];
    const float* Ws1 = (const float*)d_in[3];
    const float* Wn1 = (const float*)d_in[4];
    const float* b1  = (const float*)d_in[5];
    const float* Ws2 = (const float*)d_in[6];
    const float* Wn2 = (const float*)d_in[7];
    const float* b2  = (const float*)d_in[8];
    const float* Ws3 = (const float*)d_in[9];
    const float* Wn3 = (const float*)d_in[10];
    const float* b3  = (const float*)d_in[11];
    float* out = (float*)d_out;

    const int IN = 128, HID = 32;
    const int n_nodes = in_sizes[0] / IN;
    const int n_edges = in_sizes[1];

    char* wsb = (char*)d_ws;
    size_t off = 0;
    auto alloc = [&](size_t bytes) { char* r = wsb + off; off = (off + bytes + 255) & ~(size_t)255; return r; };
    int*   deg    = (int*)alloc((size_t)n_nodes * sizeof(int));
    int*   cursor = (int*)alloc((size_t)n_nodes * sizeof(int));
    int*   startp = (int*)alloc(((size_t)n_nodes + 1) * sizeof(int));
    float* invdeg = (float*)alloc((size_t)n_nodes * sizeof(float));
    int*   csr    = (int*)alloc((size_t)n_edges * sizeof(int));
    int*   bsum   = (int*)alloc(1024 * sizeof(int));
    int*   boff   = (int*)alloc(1024 * sizeof(int));
    float* B0     = (float*)alloc((size_t)n_nodes * HID * sizeof(float));  // pre
    float* B1     = (float*)alloc((size_t)n_nodes * HID * sizeof(float));  // p
    float* B3     = (float*)alloc((size_t)n_nodes * HID * sizeof(float));  // h

    const int gEdges = (n_edges + BLOCK - 1) / BLOCK;
    const int gNodes = (n_nodes + BLOCK - 1) / BLOCK;
    const int gP12   = (n_nodes + 127) / 128;
    const int gP3    = (n_nodes + 255) / 256;
    const int gGat   = (n_nodes + 3) / 4;      // 4 waves per block
    const int wnodes = (n_nodes + NWIN - 1) / NWIN;
    const int nchunk = (n_edges + FILL_CHUNK - 1) / FILL_CHUNK;
    const int gFill  = nchunk * NWIN;

    // ---- CSR build ----
    hipMemsetAsync(deg, 0, (size_t)n_nodes * sizeof(int), stream);
    degree_kernel<<<gEdges, BLOCK, 0, stream>>>(edge_dst, deg, n_edges);
    scanA_kernel<<<gNodes, BLOCK, 0, stream>>>(deg, bsum, n_nodes);
    scanB_kernel<<<1, 1024, 0, stream>>>(bsum, boff, startp + n_nodes, gNodes);
    scanC_kernel<<<gNodes, BLOCK, 0, stream>>>(deg, boff, startp, invdeg, cursor, n_nodes);
    fill_win<<<gFill, BLOCK, 0, stream>>>(edge_src, edge_dst, startp, cursor, csr, n_edges, wnodes);

    // ---- layer 1: 128 -> 32, relu ----
    proj_tiled<128, 32><<<gP12, BLOCK, 0, stream>>>(x, Ws1, Wn1, b1, B0, B1, n_nodes);
    gather_kernel<32, true><<<gGat, BLOCK, 0, stream>>>(B1, csr, startp, B0, invdeg, B3, n_nodes);

    // ---- layer 2: 32 -> 32, relu ----
    proj_tiled<32, 32><<<gP12, BLOCK, 0, stream>>>(B3, Ws2, Wn2, b2, B0, B1, n_nodes);
    gather_kernel<32, true><<<gGat, BLOCK, 0, stream>>>(B1, csr, startp, B0, invdeg, B3, n_nodes);

    // ---- layer 3: 32 -> 16, no relu ----
    proj_tiled<32, 16><<<gP3, BLOCK, 0, stream>>>(B3, Ws3, Wn3, b3, B0, B1, n_nodes);
    gather_kernel<16, false><<<gGat, BLOCK, 0, stream>>>(B1, csr, startp, B0, invdeg, out, n_nodes);
}

// Round 7
// 300.674 us; speedup vs baseline: 1.9796x; 1.2656x over previous
//
#include <hip/hip_runtime.h>

// GraphSAGE 3-layer (mean agg), N=100000, E=1600000, 128->32->32->16.
// Round 7: (a) CSR via bucket counting-sort — histogram(dst>>9) -> scan ->
// bucket-contiguous pair partition (~1.3x write-amp vs 16x) -> per-bucket
// LDS-staged CSR build (contiguous flush; also emits start[]/invdeg[] locally,
// replacing degree+scanA/B/C+fill = ~93us). (b) float4 sub-group gather:
// 8-16 neighbors in flight per wave (was 2) to attack the ~70us latency-bound
// gathers.

#define BLOCK 256
#define NBLK 256            // blocks for hist/part passes
#define BSH 9               // 512 nodes per bucket
#define CAP 12288           // max edges per bucket staged in LDS (mean 8192, std ~90)

// ---------------- phase 1: per-(bucket,block) histogram of dst ----------------
__global__ void hist_kernel(const int* __restrict__ dst, int* __restrict__ hist,
                            int n_edges, int nbuk, int ch) {
    __shared__ int cnt[256];
    int tid = threadIdx.x;
    for (int i = tid; i < nbuk; i += BLOCK) cnt[i] = 0;
    __syncthreads();
    int e0 = blockIdx.x * ch;
    int e1 = e0 + ch; if (e1 > n_edges) e1 = n_edges;
    for (int e = e0 + tid; e < e1; e += BLOCK)
        atomicAdd(&cnt[dst[e] >> BSH], 1);
    __syncthreads();
    for (int i = tid; i < nbuk; i += BLOCK)
        hist[i * NBLK + blockIdx.x] = cnt[i];
}

// ---------------- phase 2: exclusive scan of hist (in place), 1 block ----------------
__global__ void scanH_kernel(int* __restrict__ hist, int* __restrict__ startp,
                             int T, int n_nodes, int n_edges) {
    __shared__ int ps[1024];
    int tid = threadIdx.x;
    int per = (T + 1023) >> 10;
    int i0 = tid * per;
    int i1 = i0 + per; if (i1 > T) i1 = T;
    int s = 0;
    for (int i = i0; i < i1; ++i) s += hist[i];
    ps[tid] = s;
    __syncthreads();
    for (int off = 1; off < 1024; off <<= 1) {
        int v = (tid >= off) ? ps[tid - off] : 0;
        __syncthreads();
        ps[tid] += v;
        __syncthreads();
    }
    int run = (tid > 0) ? ps[tid - 1] : 0;
    for (int i = i0; i < i1; ++i) { int h = hist[i]; hist[i] = run; run += h; }
    if (tid == 0) startp[n_nodes] = n_edges;
}

// ---------------- phase 3: partition (src,dst) pairs bucket-contiguously ----------------
__global__ void part_kernel(const int* __restrict__ src, const int* __restrict__ dst,
                            const int* __restrict__ hist, int2* __restrict__ pairs,
                            int n_edges, int nbuk, int ch) {
    __shared__ int base[256];
    __shared__ int cnt[256];
    int tid = threadIdx.x;
    for (int i = tid; i < nbuk; i += BLOCK) {
        base[i] = hist[i * NBLK + blockIdx.x];
        cnt[i] = 0;
    }
    __syncthreads();
    int e0 = blockIdx.x * ch;
    int e1 = e0 + ch; if (e1 > n_edges) e1 = n_edges;
    for (int e = e0 + tid; e < e1; e += BLOCK) {
        int d = dst[e];
        int b = d >> BSH;
        int r = atomicAdd(&cnt[b], 1);
        pairs[base[b] + r] = make_int2(src[e], d);
    }
}

// ---------------- phase 4: per-bucket CSR build in LDS ----------------
// Emits start[], invdeg[], csr_src[] for its 512-node slice; contiguous flush.
__global__ void build_kernel(const int2* __restrict__ pairs, const int* __restrict__ hist,
                             int* __restrict__ start, float* __restrict__ invdeg,
                             int* __restrict__ csr_src, int n_nodes, int n_edges, int nbuk) {
    __shared__ int deg[512];
    __shared__ int lst[512];
    __shared__ int cur[512];
    __shared__ int wps[4];
    __shared__ int scsr[CAP];

    int b = blockIdx.x;
    int tid = threadIdx.x;
    int e0 = hist[b * NBLK];
    int e1 = (b + 1 < nbuk) ? hist[(b + 1) * NBLK] : n_edges;
    int lo = b << BSH;
    int hi = lo + (1 << BSH); if (hi > n_nodes) hi = n_nodes;
    int nn = hi - lo;
    int ne = e1 - e0;

    for (int i = tid; i < 512; i += BLOCK) deg[i] = 0;
    __syncthreads();
    for (int i = e0 + tid; i < e1; i += BLOCK)
        atomicAdd(&deg[pairs[i].y - lo], 1);
    __syncthreads();

    // exclusive scan over 512 degrees: thread t owns entries 2t, 2t+1
    int d0 = deg[2 * tid], d1 = deg[2 * tid + 1];
    int s = d0 + d1;
    int lane = tid & 63, w = tid >> 6;
    int v = s;
#pragma unroll
    for (int off = 1; off < 64; off <<= 1) {
        int u = __shfl_up(v, off);
        if (lane >= off) v += u;
    }
    if (lane == 63) wps[w] = v;
    __syncthreads();
    int wb = 0;
    for (int k = 0; k < w; ++k) wb += wps[k];
    int excl = wb + v - s;
    lst[2 * tid] = excl;
    lst[2 * tid + 1] = excl + d0;
    cur[2 * tid] = 0;
    cur[2 * tid + 1] = 0;
    __syncthreads();

    for (int i = tid; i < nn; i += BLOCK) {
        start[lo + i] = e0 + lst[i];
        int d = deg[i];
        invdeg[lo + i] = 1.0f / (float)(d < 1 ? 1 : d);
    }

    if (ne <= CAP) {
        for (int i = e0 + tid; i < e1; i += BLOCK) {
            int2 pr = pairs[i];
            int dl = pr.y - lo;
            int sl = lst[dl] + atomicAdd(&cur[dl], 1);
            scsr[sl] = pr.x;
        }
        __syncthreads();
        for (int i = tid; i < ne; i += BLOCK) csr_src[e0 + i] = scsr[i];
    } else {
        // fallback (shouldn't trigger for this graph): direct global scatter
        for (int i = e0 + tid; i < e1; i += BLOCK) {
            int2 pr = pairs[i];
            int dl = pr.y - lo;
            int sl = lst[dl] + atomicAdd(&cur[dl], 1);
            csr_src[e0 + sl] = pr.x;
        }
    }
}

// ---------------- register-tiled projection: pre = h@Ws + b ; p = h@Wn ----------------
template<int DIN, int DOUT>
__global__ __launch_bounds__(256, 2)
void proj_tiled(const float* __restrict__ h,
                const float* __restrict__ Ws,
                const float* __restrict__ Wn,
                const float* __restrict__ bias,
                float* __restrict__ pre,
                float* __restrict__ p,
                int n_nodes) {
    constexpr int OD  = 2 * DOUT;
    constexpr int OPT = 8;
    constexpr int OG  = OD / OPT;
    constexpr int NPT = 4;
    constexpr int NG  = 256 / OG;
    constexpr int NT  = NPT * NG;
    constexpr int KC  = 32;
    constexpr int NCH = DIN / KC;

    __shared__ float sW[DIN][OD];
    __shared__ float sx[NT][KC + 1];
    __shared__ float sb[DOUT];

    const int tid = threadIdx.x;
    for (int i = tid; i < DIN * OD; i += 256) {
        int k = i / OD, o = i % OD;
        sW[k][o] = (o < DOUT) ? Ws[k * DOUT + o] : Wn[k * DOUT + (o - DOUT)];
    }
    if (tid < DOUT) sb[tid] = bias[tid];

    const int to = tid % OG;
    const int tn = tid / OG;
    const int o0 = to * OPT;
    const int node0 = blockIdx.x * NT;

    float acc[NPT][OPT];
#pragma unroll
    for (int n = 0; n < NPT; ++n)
#pragma unroll
        for (int o = 0; o < OPT; ++o) acc[n][o] = 0.f;

    constexpr int L4 = NT * KC / (256 * 4);
    for (int c = 0; c < NCH; ++c) {
        if (c > 0) __syncthreads();
#pragma unroll
        for (int q = 0; q < L4; ++q) {
            int fq   = q * 256 + tid;
            int node = fq / (KC / 4);
            int kq   = fq % (KC / 4);
            float4 v = make_float4(0.f, 0.f, 0.f, 0.f);
            int gn = node0 + node;
            if (gn < n_nodes)
                v = *reinterpret_cast<const float4*>(h + (size_t)gn * DIN + c * KC + kq * 4);
            sx[node][kq * 4 + 0] = v.x;
            sx[node][kq * 4 + 1] = v.y;
            sx[node][kq * 4 + 2] = v.z;
            sx[node][kq * 4 + 3] = v.w;
        }
        __syncthreads();

#pragma unroll 8
        for (int k = 0; k < KC; ++k) {
            const float4 wa = *reinterpret_cast<const float4*>(&sW[c * KC + k][o0]);
            const float4 wb = *reinterpret_cast<const float4*>(&sW[c * KC + k][o0 + 4]);
            float xv[NPT];
#pragma unroll
            for (int n = 0; n < NPT; ++n) xv[n] = sx[tn * NPT + n][k];
#pragma unroll
            for (int n = 0; n < NPT; ++n) {
                acc[n][0] = fmaf(xv[n], wa.x, acc[n][0]);
                acc[n][1] = fmaf(xv[n], wa.y, acc[n][1]);
                acc[n][2] = fmaf(xv[n], wa.z, acc[n][2]);
                acc[n][3] = fmaf(xv[n], wa.w, acc[n][3]);
                acc[n][4] = fmaf(xv[n], wb.x, acc[n][4]);
                acc[n][5] = fmaf(xv[n], wb.y, acc[n][5]);
                acc[n][6] = fmaf(xv[n], wb.z, acc[n][6]);
                acc[n][7] = fmaf(xv[n], wb.w, acc[n][7]);
            }
        }
    }

    const bool self_half = (o0 < DOUT);
#pragma unroll
    for (int n = 0; n < NPT; ++n) {
        int node = node0 + tn * NPT + n;
        if (node >= n_nodes) continue;
        if (self_half) {
            float4 r0 = make_float4(acc[n][0] + sb[o0 + 0], acc[n][1] + sb[o0 + 1],
                                    acc[n][2] + sb[o0 + 2], acc[n][3] + sb[o0 + 3]);
            float4 r1 = make_float4(acc[n][4] + sb[o0 + 4], acc[n][5] + sb[o0 + 5],
                                    acc[n][6] + sb[o0 + 6], acc[n][7] + sb[o0 + 7]);
            *reinterpret_cast<float4*>(pre + (size_t)node * DOUT + o0)     = r0;
            *reinterpret_cast<float4*>(pre + (size_t)node * DOUT + o0 + 4) = r1;
        } else {
            int oo = o0 - DOUT;
            float4 r0 = make_float4(acc[n][0], acc[n][1], acc[n][2], acc[n][3]);
            float4 r1 = make_float4(acc[n][4], acc[n][5], acc[n][6], acc[n][7]);
            *reinterpret_cast<float4*>(p + (size_t)node * DOUT + oo)     = r0;
            *reinterpret_cast<float4*>(p + (size_t)node * DOUT + oo + 4) = r1;
        }
    }
}

// ---------------- float4 sub-group gather + finalize ----------------
// Wave = (64*4/D) neighbor sub-groups x (D/4) float4 lanes; unroll 2.
template<int D, bool RELU>
__global__ void gather_kernel(const float* __restrict__ p,
                              const int* __restrict__ csr_src,
                              const int* __restrict__ start,
                              const float* __restrict__ pre,
                              const float* __restrict__ invdeg,
                              float* __restrict__ out,
                              int n_nodes) {
    constexpr int LPN = D / 4;          // lanes per neighbor (8 or 4)
    constexpr int NPG = 64 / LPN;       // neighbors in flight (8 or 16)
    int wave = threadIdx.x >> 6;
    int lane = threadIdx.x & 63;
    int g = blockIdx.x * (blockDim.x >> 6) + wave;
    if (g >= n_nodes) return;
    int sub = lane / LPN;
    int fl  = lane % LPN;               // float4 index within row
    int s0 = start[g];
    int s1 = start[g + 1];
    const float4* __restrict__ p4 = reinterpret_cast<const float4*>(p);
    float4 a0 = make_float4(0.f, 0.f, 0.f, 0.f);
    float4 a1 = make_float4(0.f, 0.f, 0.f, 0.f);
    int j = s0 + sub;
    for (; j + NPG < s1; j += 2 * NPG) {
        int c0 = csr_src[j];
        int c1 = csr_src[j + NPG];
        float4 v0 = p4[c0 * LPN + fl];
        float4 v1 = p4[c1 * LPN + fl];
        a0.x += v0.x; a0.y += v0.y; a0.z += v0.z; a0.w += v0.w;
        a1.x += v1.x; a1.y += v1.y; a1.z += v1.z; a1.w += v1.w;
    }
    if (j < s1) {
        float4 v = p4[csr_src[j] * LPN + fl];
        a0.x += v.x; a0.y += v.y; a0.z += v.z; a0.w += v.w;
    }
    float4 a = make_float4(a0.x + a1.x, a0.y + a1.y, a0.z + a1.z, a0.w + a1.w);
#pragma unroll
    for (int off = 32; off >= LPN; off >>= 1) {
        a.x += __shfl_down(a.x, off);
        a.y += __shfl_down(a.y, off);
        a.z += __shfl_down(a.z, off);
        a.w += __shfl_down(a.w, off);
    }
    if (lane < LPN) {
        float id = invdeg[g];
        float4 pr = reinterpret_cast<const float4*>(pre)[g * LPN + fl];
        float4 r;
        r.x = pr.x + a.x * id;
        r.y = pr.y + a.y * id;
        r.z = pr.z + a.z * id;
        r.w = pr.w + a.w * id;
        if (RELU) {
            r.x = fmaxf(r.x, 0.f); r.y = fmaxf(r.y, 0.f);
            r.z = fmaxf(r.z, 0.f); r.w = fmaxf(r.w, 0.f);
        }
        reinterpret_cast<float4*>(out)[g * LPN + fl] = r;
    }
}

extern "C" void kernel_launch(void* const* d_in, const int* in_sizes, int n_in,
                              void* d_out, int out_size, void* d_ws, size_t ws_size,
                              hipStream_t stream) {
    const float* x        = (const float*)d_in[0];
    const int*   edge_src = (const int*)d_in[1];
    const int*   edge_dst = (const int*)d_in[2];
    const float* Ws1 = (const float*)d_in[3];
    const float* Wn1 = (const float*)d_in[4];
    const float* b1  = (const float*)d_in[5];
    const float* Ws2 = (const float*)d_in[6];
    const float* Wn2 = (const float*)d_in[7];
    const float* b2  = (const float*)d_in[8];
    const float* Ws3 = (const float*)d_in[9];
    const float* Wn3 = (const float*)d_in[10];
    const float* b3  = (const float*)d_in[11];
    float* out = (float*)d_out;

    const int IN = 128, HID = 32;
    const int n_nodes = in_sizes[0] / IN;
    const int n_edges = in_sizes[1];
    const int nbuk = (n_nodes + (1 << BSH) - 1) >> BSH;   // 196
    const int ch   = (n_edges + NBLK - 1) / NBLK;         // 6250

    char* wsb = (char*)d_ws;
    size_t off = 0;
    auto alloc = [&](size_t bytes) { char* r = wsb + off; off = (off + bytes + 255) & ~(size_t)255; return r; };
    int*   startp = (int*)alloc(((size_t)n_nodes + 1) * sizeof(int));
    float* invdeg = (float*)alloc((size_t)n_nodes * sizeof(float));
    int*   csr    = (int*)alloc((size_t)n_edges * sizeof(int));
    int*   hist   = (int*)alloc((size_t)nbuk * NBLK * sizeof(int));
    float* B0     = (float*)alloc((size_t)n_nodes * HID * sizeof(float));  // pre
    float* B1     = (float*)alloc((size_t)n_nodes * HID * sizeof(float));  // p
    float* B3     = (float*)alloc((size_t)n_nodes * HID * sizeof(float));  // h
    // pairs aliases B0: CSR build fully precedes proj1 on the stream.
    int2*  pairs  = (int2*)B0;   // n_edges*8 = 12.8MB == B0 size

    const int gP12   = (n_nodes + 127) / 128;
    const int gP3    = (n_nodes + 255) / 256;
    const int gGat   = (n_nodes + 3) / 4;      // 4 waves per block

    // ---- CSR build: hist -> scan -> partition -> per-bucket build ----
    hist_kernel <<<NBLK, BLOCK, 0, stream>>>(edge_dst, hist, n_edges, nbuk, ch);
    scanH_kernel<<<1, 1024, 0, stream>>>(hist, startp, nbuk * NBLK, n_nodes, n_edges);
    part_kernel <<<NBLK, BLOCK, 0, stream>>>(edge_src, edge_dst, hist, pairs, n_edges, nbuk, ch);
    build_kernel<<<nbuk, BLOCK, 0, stream>>>(pairs, hist, startp, invdeg, csr, n_nodes, n_edges, nbuk);

    // ---- layer 1: 128 -> 32, relu ----
    proj_tiled<128, 32><<<gP12, BLOCK, 0, stream>>>(x, Ws1, Wn1, b1, B0, B1, n_nodes);
    gather_kernel<32, true><<<gGat, BLOCK, 0, stream>>>(B1, csr, startp, B0, invdeg, B3, n_nodes);

    // ---- layer 2: 32 -> 32, relu ----
    proj_tiled<32, 32><<<gP12, BLOCK, 0, stream>>>(B3, Ws2, Wn2, b2, B0, B1, n_nodes);
    gather_kernel<32, true><<<gGat, BLOCK, 0, stream>>>(B1, csr, startp, B0, invdeg, B3, n_nodes);

    // ---- layer 3: 32 -> 16, no relu ----
    proj_tiled<32, 16><<<gP3, BLOCK, 0, stream>>>(B3, Ws3, Wn3, b3, B0, B1, n_nodes);
    gather_kernel<16, false><<<gGat, BLOCK, 0, stream>>>(B1, csr, startp, B0, invdeg, out, n_nodes);
}

// Round 8
// 230.250 us; speedup vs baseline: 2.5851x; 1.3059x over previous
//
#include <hip/hip_runtime.h>

// GraphSAGE 3-layer (mean agg), N=100000, E=1600000, 128->32->32->16.
// Round 8: round 7 + parallel hierarchical hist-scan. Round 7's scanH was a
// single 1024-thread block walking 50K entries serially = 77us on one CU
// (same class of bug as round 2's scan). Now: per-bucket in-block scan (196
// blocks) -> bucket-total scan (1 block, 1 entry/thread) -> offset add.

#define BLOCK 256
#define NBLK 256            // blocks for hist/part passes
#define BSH 9               // 512 nodes per bucket
#define CAP 12288           // max edges per bucket staged in LDS

// ---------------- phase 1: per-(bucket,block) histogram of dst ----------------
__global__ void hist_kernel(const int* __restrict__ dst, int* __restrict__ hist,
                            int n_edges, int nbuk, int ch) {
    __shared__ int cnt[256];
    int tid = threadIdx.x;
    for (int i = tid; i < nbuk; i += BLOCK) cnt[i] = 0;
    __syncthreads();
    int e0 = blockIdx.x * ch;
    int e1 = e0 + ch; if (e1 > n_edges) e1 = n_edges;
    for (int e = e0 + tid; e < e1; e += BLOCK)
        atomicAdd(&cnt[dst[e] >> BSH], 1);
    __syncthreads();
    for (int i = tid; i < nbuk; i += BLOCK)
        hist[i * NBLK + blockIdx.x] = cnt[i];
}

// ---------------- phase 2a: per-bucket exclusive scan of its 256 block-counts ----------------
__global__ void scanBlk_kernel(int* __restrict__ hist, int* __restrict__ buktot) {
    int b = blockIdx.x;
    int tid = threadIdx.x;              // 256 threads == NBLK entries
    int orig = hist[b * NBLK + tid];
    int v = orig;
    int lane = tid & 63, w = tid >> 6;
#pragma unroll
    for (int off = 1; off < 64; off <<= 1) {
        int u = __shfl_up(v, off);
        if (lane >= off) v += u;
    }
    __shared__ int wps[4];
    if (lane == 63) wps[w] = v;
    __syncthreads();
    int wadd = 0;
    for (int k = 0; k < w; ++k) wadd += wps[k];
    int excl = v - orig + wadd;
    hist[b * NBLK + tid] = excl;
    if (tid == 255) buktot[b] = excl + orig;
}

// ---------------- phase 2b: exclusive scan of bucket totals (1 block) ----------------
__global__ void scanBuk_kernel(const int* __restrict__ buktot, int* __restrict__ bukoff,
                               int nbuk, int* __restrict__ startp, int n_nodes, int n_edges) {
    int tid = threadIdx.x;              // 256 threads >= nbuk
    int orig = (tid < nbuk) ? buktot[tid] : 0;
    int v = orig;
    int lane = tid & 63, w = tid >> 6;
#pragma unroll
    for (int off = 1; off < 64; off <<= 1) {
        int u = __shfl_up(v, off);
        if (lane >= off) v += u;
    }
    __shared__ int wps[4];
    if (lane == 63) wps[w] = v;
    __syncthreads();
    int wadd = 0;
    for (int k = 0; k < w; ++k) wadd += wps[k];
    int excl = v - orig + wadd;
    if (tid < nbuk) bukoff[tid] = excl;
    if (tid == 0) startp[n_nodes] = n_edges;
}

// ---------------- phase 2c: add bucket offsets back ----------------
__global__ void addOff_kernel(int* __restrict__ hist, const int* __restrict__ bukoff) {
    hist[blockIdx.x * NBLK + threadIdx.x] += bukoff[blockIdx.x];
}

// ---------------- phase 3: partition (src,dst) pairs bucket-contiguously ----------------
__global__ void part_kernel(const int* __restrict__ src, const int* __restrict__ dst,
                            const int* __restrict__ hist, int2* __restrict__ pairs,
                            int n_edges, int nbuk, int ch) {
    __shared__ int base[256];
    __shared__ int cnt[256];
    int tid = threadIdx.x;
    for (int i = tid; i < nbuk; i += BLOCK) {
        base[i] = hist[i * NBLK + blockIdx.x];
        cnt[i] = 0;
    }
    __syncthreads();
    int e0 = blockIdx.x * ch;
    int e1 = e0 + ch; if (e1 > n_edges) e1 = n_edges;
    for (int e = e0 + tid; e < e1; e += BLOCK) {
        int d = dst[e];
        int b = d >> BSH;
        int r = atomicAdd(&cnt[b], 1);
        pairs[base[b] + r] = make_int2(src[e], d);
    }
}

// ---------------- phase 4: per-bucket CSR build in LDS ----------------
__global__ void build_kernel(const int2* __restrict__ pairs, const int* __restrict__ hist,
                             int* __restrict__ start, float* __restrict__ invdeg,
                             int* __restrict__ csr_src, int n_nodes, int n_edges, int nbuk) {
    __shared__ int deg[512];
    __shared__ int lst[512];
    __shared__ int cur[512];
    __shared__ int wps[4];
    __shared__ int scsr[CAP];

    int b = blockIdx.x;
    int tid = threadIdx.x;
    int e0 = hist[b * NBLK];
    int e1 = (b + 1 < nbuk) ? hist[(b + 1) * NBLK] : n_edges;
    int lo = b << BSH;
    int hi = lo + (1 << BSH); if (hi > n_nodes) hi = n_nodes;
    int nn = hi - lo;
    int ne = e1 - e0;

    for (int i = tid; i < 512; i += BLOCK) deg[i] = 0;
    __syncthreads();
    for (int i = e0 + tid; i < e1; i += BLOCK)
        atomicAdd(&deg[pairs[i].y - lo], 1);
    __syncthreads();

    int d0 = deg[2 * tid], d1 = deg[2 * tid + 1];
    int s = d0 + d1;
    int lane = tid & 63, w = tid >> 6;
    int v = s;
#pragma unroll
    for (int off = 1; off < 64; off <<= 1) {
        int u = __shfl_up(v, off);
        if (lane >= off) v += u;
    }
    if (lane == 63) wps[w] = v;
    __syncthreads();
    int wb = 0;
    for (int k = 0; k < w; ++k) wb += wps[k];
    int excl = wb + v - s;
    lst[2 * tid] = excl;
    lst[2 * tid + 1] = excl + d0;
    cur[2 * tid] = 0;
    cur[2 * tid + 1] = 0;
    __syncthreads();

    for (int i = tid; i < nn; i += BLOCK) {
        start[lo + i] = e0 + lst[i];
        int d = deg[i];
        invdeg[lo + i] = 1.0f / (float)(d < 1 ? 1 : d);
    }

    if (ne <= CAP) {
        for (int i = e0 + tid; i < e1; i += BLOCK) {
            int2 pr = pairs[i];
            int dl = pr.y - lo;
            int sl = lst[dl] + atomicAdd(&cur[dl], 1);
            scsr[sl] = pr.x;
        }
        __syncthreads();
        for (int i = tid; i < ne; i += BLOCK) csr_src[e0 + i] = scsr[i];
    } else {
        for (int i = e0 + tid; i < e1; i += BLOCK) {
            int2 pr = pairs[i];
            int dl = pr.y - lo;
            int sl = lst[dl] + atomicAdd(&cur[dl], 1);
            csr_src[e0 + sl] = pr.x;
        }
    }
}

// ---------------- register-tiled projection: pre = h@Ws + b ; p = h@Wn ----------------
template<int DIN, int DOUT>
__global__ __launch_bounds__(256, 2)
void proj_tiled(const float* __restrict__ h,
                const float* __restrict__ Ws,
                const float* __restrict__ Wn,
                const float* __restrict__ bias,
                float* __restrict__ pre,
                float* __restrict__ p,
                int n_nodes) {
    constexpr int OD  = 2 * DOUT;
    constexpr int OPT = 8;
    constexpr int OG  = OD / OPT;
    constexpr int NPT = 4;
    constexpr int NG  = 256 / OG;
    constexpr int NT  = NPT * NG;
    constexpr int KC  = 32;
    constexpr int NCH = DIN / KC;

    __shared__ float sW[DIN][OD];
    __shared__ float sx[NT][KC + 1];
    __shared__ float sb[DOUT];

    const int tid = threadIdx.x;
    for (int i = tid; i < DIN * OD; i += 256) {
        int k = i / OD, o = i % OD;
        sW[k][o] = (o < DOUT) ? Ws[k * DOUT + o] : Wn[k * DOUT + (o - DOUT)];
    }
    if (tid < DOUT) sb[tid] = bias[tid];

    const int to = tid % OG;
    const int tn = tid / OG;
    const int o0 = to * OPT;
    const int node0 = blockIdx.x * NT;

    float acc[NPT][OPT];
#pragma unroll
    for (int n = 0; n < NPT; ++n)
#pragma unroll
        for (int o = 0; o < OPT; ++o) acc[n][o] = 0.f;

    constexpr int L4 = NT * KC / (256 * 4);
    for (int c = 0; c < NCH; ++c) {
        if (c > 0) __syncthreads();
#pragma unroll
        for (int q = 0; q < L4; ++q) {
            int fq   = q * 256 + tid;
            int node = fq / (KC / 4);
            int kq   = fq % (KC / 4);
            float4 v = make_float4(0.f, 0.f, 0.f, 0.f);
            int gn = node0 + node;
            if (gn < n_nodes)
                v = *reinterpret_cast<const float4*>(h + (size_t)gn * DIN + c * KC + kq * 4);
            sx[node][kq * 4 + 0] = v.x;
            sx[node][kq * 4 + 1] = v.y;
            sx[node][kq * 4 + 2] = v.z;
            sx[node][kq * 4 + 3] = v.w;
        }
        __syncthreads();

#pragma unroll 8
        for (int k = 0; k < KC; ++k) {
            const float4 wa = *reinterpret_cast<const float4*>(&sW[c * KC + k][o0]);
            const float4 wb = *reinterpret_cast<const float4*>(&sW[c * KC + k][o0 + 4]);
            float xv[NPT];
#pragma unroll
            for (int n = 0; n < NPT; ++n) xv[n] = sx[tn * NPT + n][k];
#pragma unroll
            for (int n = 0; n < NPT; ++n) {
                acc[n][0] = fmaf(xv[n], wa.x, acc[n][0]);
                acc[n][1] = fmaf(xv[n], wa.y, acc[n][1]);
                acc[n][2] = fmaf(xv[n], wa.z, acc[n][2]);
                acc[n][3] = fmaf(xv[n], wa.w, acc[n][3]);
                acc[n][4] = fmaf(xv[n], wb.x, acc[n][4]);
                acc[n][5] = fmaf(xv[n], wb.y, acc[n][5]);
                acc[n][6] = fmaf(xv[n], wb.z, acc[n][6]);
                acc[n][7] = fmaf(xv[n], wb.w, acc[n][7]);
            }
        }
    }

    const bool self_half = (o0 < DOUT);
#pragma unroll
    for (int n = 0; n < NPT; ++n) {
        int node = node0 + tn * NPT + n;
        if (node >= n_nodes) continue;
        if (self_half) {
            float4 r0 = make_float4(acc[n][0] + sb[o0 + 0], acc[n][1] + sb[o0 + 1],
                                    acc[n][2] + sb[o0 + 2], acc[n][3] + sb[o0 + 3]);
            float4 r1 = make_float4(acc[n][4] + sb[o0 + 4], acc[n][5] + sb[o0 + 5],
                                    acc[n][6] + sb[o0 + 6], acc[n][7] + sb[o0 + 7]);
            *reinterpret_cast<float4*>(pre + (size_t)node * DOUT + o0)     = r0;
            *reinterpret_cast<float4*>(pre + (size_t)node * DOUT + o0 + 4) = r1;
        } else {
            int oo = o0 - DOUT;
            float4 r0 = make_float4(acc[n][0], acc[n][1], acc[n][2], acc[n][3]);
            float4 r1 = make_float4(acc[n][4], acc[n][5], acc[n][6], acc[n][7]);
            *reinterpret_cast<float4*>(p + (size_t)node * DOUT + oo)     = r0;
            *reinterpret_cast<float4*>(p + (size_t)node * DOUT + oo + 4) = r1;
        }
    }
}

// ---------------- float4 sub-group gather + finalize ----------------
template<int D, bool RELU>
__global__ void gather_kernel(const float* __restrict__ p,
                              const int* __restrict__ csr_src,
                              const int* __restrict__ start,
                              const float* __restrict__ pre,
                              const float* __restrict__ invdeg,
                              float* __restrict__ out,
                              int n_nodes) {
    constexpr int LPN = D / 4;
    constexpr int NPG = 64 / LPN;
    int wave = threadIdx.x >> 6;
    int lane = threadIdx.x & 63;
    int g = blockIdx.x * (blockDim.x >> 6) + wave;
    if (g >= n_nodes) return;
    int sub = lane / LPN;
    int fl  = lane % LPN;
    int s0 = start[g];
    int s1 = start[g + 1];
    const float4* __restrict__ p4 = reinterpret_cast<const float4*>(p);
    float4 a0 = make_float4(0.f, 0.f, 0.f, 0.f);
    float4 a1 = make_float4(0.f, 0.f, 0.f, 0.f);
    int j = s0 + sub;
    for (; j + NPG < s1; j += 2 * NPG) {
        int c0 = csr_src[j];
        int c1 = csr_src[j + NPG];
        float4 v0 = p4[c0 * LPN + fl];
        float4 v1 = p4[c1 * LPN + fl];
        a0.x += v0.x; a0.y += v0.y; a0.z += v0.z; a0.w += v0.w;
        a1.x += v1.x; a1.y += v1.y; a1.z += v1.z; a1.w += v1.w;
    }
    if (j < s1) {
        float4 v = p4[csr_src[j] * LPN + fl];
        a0.x += v.x; a0.y += v.y; a0.z += v.z; a0.w += v.w;
    }
    float4 a = make_float4(a0.x + a1.x, a0.y + a1.y, a0.z + a1.z, a0.w + a1.w);
#pragma unroll
    for (int off = 32; off >= LPN; off >>= 1) {
        a.x += __shfl_down(a.x, off);
        a.y += __shfl_down(a.y, off);
        a.z += __shfl_down(a.z, off);
        a.w += __shfl_down(a.w, off);
    }
    if (lane < LPN) {
        float id = invdeg[g];
        float4 pr = reinterpret_cast<const float4*>(pre)[g * LPN + fl];
        float4 r;
        r.x = pr.x + a.x * id;
        r.y = pr.y + a.y * id;
        r.z = pr.z + a.z * id;
        r.w = pr.w + a.w * id;
        if (RELU) {
            r.x = fmaxf(r.x, 0.f); r.y = fmaxf(r.y, 0.f);
            r.z = fmaxf(r.z, 0.f); r.w = fmaxf(r.w, 0.f);
        }
        reinterpret_cast<float4*>(out)[g * LPN + fl] = r;
    }
}

extern "C" void kernel_launch(void* const* d_in, const int* in_sizes, int n_in,
                              void* d_out, int out_size, void* d_ws, size_t ws_size,
                              hipStream_t stream) {
    const float* x        = (const float*)d_in[0];
    const int*   edge_src = (const int*)d_in[1];
    const int*   edge_dst = (const int*)d_in[2];
    const float* Ws1 = (const float*)d_in[3];
    const float* Wn1 = (const float*)d_in[4];
    const float* b1  = (const float*)d_in[5];
    const float* Ws2 = (const float*)d_in[6];
    const float* Wn2 = (const float*)d_in[7];
    const float* b2  = (const float*)d_in[8];
    const float* Ws3 = (const float*)d_in[9];
    const float* Wn3 = (const float*)d_in[10];
    const float* b3  = (const float*)d_in[11];
    float* out = (float*)d_out;

    const int IN = 128, HID = 32;
    const int n_nodes = in_sizes[0] / IN;
    const int n_edges = in_sizes[1];
    const int nbuk = (n_nodes + (1 << BSH) - 1) >> BSH;   // 196
    const int ch   = (n_edges + NBLK - 1) / NBLK;         // 6250

    char* wsb = (char*)d_ws;
    size_t off = 0;
    auto alloc = [&](size_t bytes) { char* r = wsb + off; off = (off + bytes + 255) & ~(size_t)255; return r; };
    int*   startp = (int*)alloc(((size_t)n_nodes + 1) * sizeof(int));
    float* invdeg = (float*)alloc((size_t)n_nodes * sizeof(float));
    int*   csr    = (int*)alloc((size_t)n_edges * sizeof(int));
    int*   hist   = (int*)alloc((size_t)nbuk * NBLK * sizeof(int));
    int*   buktot = (int*)alloc(256 * sizeof(int));
    int*   bukoff = (int*)alloc(256 * sizeof(int));
    float* B0     = (float*)alloc((size_t)n_nodes * HID * sizeof(float));  // pre
    float* B1     = (float*)alloc((size_t)n_nodes * HID * sizeof(float));  // p
    float* B3     = (float*)alloc((size_t)n_nodes * HID * sizeof(float));  // h
    int2*  pairs  = (int2*)B0;   // CSR build fully precedes proj1 on the stream

    const int gP12   = (n_nodes + 127) / 128;
    const int gP3    = (n_nodes + 255) / 256;
    const int gGat   = (n_nodes + 3) / 4;

    // ---- CSR build: hist -> hierarchical scan -> partition -> per-bucket build ----
    hist_kernel   <<<NBLK, BLOCK, 0, stream>>>(edge_dst, hist, n_edges, nbuk, ch);
    scanBlk_kernel<<<nbuk, BLOCK, 0, stream>>>(hist, buktot);
    scanBuk_kernel<<<1, BLOCK, 0, stream>>>(buktot, bukoff, nbuk, startp, n_nodes, n_edges);
    addOff_kernel <<<nbuk, BLOCK, 0, stream>>>(hist, bukoff);
    part_kernel   <<<NBLK, BLOCK, 0, stream>>>(edge_src, edge_dst, hist, pairs, n_edges, nbuk, ch);
    build_kernel  <<<nbuk, BLOCK, 0, stream>>>(pairs, hist, startp, invdeg, csr, n_nodes, n_edges, nbuk);

    // ---- layer 1: 128 -> 32, relu ----
    proj_tiled<128, 32><<<gP12, BLOCK, 0, stream>>>(x, Ws1, Wn1, b1, B0, B1, n_nodes);
    gather_kernel<32, true><<<gGat, BLOCK, 0, stream>>>(B1, csr, startp, B0, invdeg, B3, n_nodes);

    // ---- layer 2: 32 -> 32, relu ----
    proj_tiled<32, 32><<<gP12, BLOCK, 0, stream>>>(B3, Ws2, Wn2, b2, B0, B1, n_nodes);
    gather_kernel<32, true><<<gGat, BLOCK, 0, stream>>>(B1, csr, startp, B0, invdeg, B3, n_nodes);

    // ---- layer 3: 32 -> 16, no relu ----
    proj_tiled<32, 16><<<gP3, BLOCK, 0, stream>>>(B3, Ws3, Wn3, b3, B0, B1, n_nodes);
    gather_kernel<16, false><<<gGat, BLOCK, 0, stream>>>(B1, csr, startp, B0, invdeg, out, n_nodes);
}

// Round 9
// 222.715 us; speedup vs baseline: 2.6726x; 1.0338x over previous
//
#include <hip/hip_runtime.h>

// GraphSAGE 3-layer (mean agg), N=100000, E=1600000, 128->32->32->16.
// Round 9: round 8 + (a) K-chunked W staging in proj (LDS 50KB->25KB; round 8
// was occupancy-capped at 2 blocks/CU, 16% occupancy, latency-bound at 25%
// VALUBusy), (b) addOff folded into part/build (one fewer launch).

#define BLOCK 256
#define NBLK 256            // blocks for hist/part passes
#define BSH 9               // 512 nodes per bucket
#define CAP 12288           // max edges per bucket staged in LDS

// ---------------- phase 1: per-(bucket,block) histogram of dst ----------------
__global__ void hist_kernel(const int* __restrict__ dst, int* __restrict__ hist,
                            int n_edges, int nbuk, int ch) {
    __shared__ int cnt[256];
    int tid = threadIdx.x;
    for (int i = tid; i < nbuk; i += BLOCK) cnt[i] = 0;
    __syncthreads();
    int e0 = blockIdx.x * ch;
    int e1 = e0 + ch; if (e1 > n_edges) e1 = n_edges;
    for (int e = e0 + tid; e < e1; e += BLOCK)
        atomicAdd(&cnt[dst[e] >> BSH], 1);
    __syncthreads();
    for (int i = tid; i < nbuk; i += BLOCK)
        hist[i * NBLK + blockIdx.x] = cnt[i];
}

// ---------------- phase 2a: per-bucket exclusive scan of its 256 block-counts ----------------
__global__ void scanBlk_kernel(int* __restrict__ hist, int* __restrict__ buktot) {
    int b = blockIdx.x;
    int tid = threadIdx.x;
    int orig = hist[b * NBLK + tid];
    int v = orig;
    int lane = tid & 63, w = tid >> 6;
#pragma unroll
    for (int off = 1; off < 64; off <<= 1) {
        int u = __shfl_up(v, off);
        if (lane >= off) v += u;
    }
    __shared__ int wps[4];
    if (lane == 63) wps[w] = v;
    __syncthreads();
    int wadd = 0;
    for (int k = 0; k < w; ++k) wadd += wps[k];
    int excl = v - orig + wadd;
    hist[b * NBLK + tid] = excl;
    if (tid == 255) buktot[b] = excl + orig;
}

// ---------------- phase 2b: exclusive scan of bucket totals (1 block) ----------------
__global__ void scanBuk_kernel(const int* __restrict__ buktot, int* __restrict__ bukoff,
                               int nbuk, int* __restrict__ startp, int n_nodes, int n_edges) {
    int tid = threadIdx.x;
    int orig = (tid < nbuk) ? buktot[tid] : 0;
    int v = orig;
    int lane = tid & 63, w = tid >> 6;
#pragma unroll
    for (int off = 1; off < 64; off <<= 1) {
        int u = __shfl_up(v, off);
        if (lane >= off) v += u;
    }
    __shared__ int wps[4];
    if (lane == 63) wps[w] = v;
    __syncthreads();
    int wadd = 0;
    for (int k = 0; k < w; ++k) wadd += wps[k];
    int excl = v - orig + wadd;
    if (tid < nbuk) bukoff[tid] = excl;
    if (tid == 0) { bukoff[nbuk] = n_edges; startp[n_nodes] = n_edges; }
}

// ---------------- phase 3: partition (src,dst) pairs bucket-contiguously ----------------
__global__ void part_kernel(const int* __restrict__ src, const int* __restrict__ dst,
                            const int* __restrict__ hist, const int* __restrict__ bukoff,
                            int2* __restrict__ pairs, int n_edges, int nbuk, int ch) {
    __shared__ int base[256];
    __shared__ int cnt[256];
    int tid = threadIdx.x;
    for (int i = tid; i < nbuk; i += BLOCK) {
        base[i] = hist[i * NBLK + blockIdx.x] + bukoff[i];
        cnt[i] = 0;
    }
    __syncthreads();
    int e0 = blockIdx.x * ch;
    int e1 = e0 + ch; if (e1 > n_edges) e1 = n_edges;
    for (int e = e0 + tid; e < e1; e += BLOCK) {
        int d = dst[e];
        int b = d >> BSH;
        int r = atomicAdd(&cnt[b], 1);
        pairs[base[b] + r] = make_int2(src[e], d);
    }
}

// ---------------- phase 4: per-bucket CSR build in LDS ----------------
__global__ void build_kernel(const int2* __restrict__ pairs, const int* __restrict__ bukoff,
                             int* __restrict__ start, float* __restrict__ invdeg,
                             int* __restrict__ csr_src, int n_nodes) {
    __shared__ int deg[512];
    __shared__ int lst[512];
    __shared__ int cur[512];
    __shared__ int wps[4];
    __shared__ int scsr[CAP];

    int b = blockIdx.x;
    int tid = threadIdx.x;
    int e0 = bukoff[b];
    int e1 = bukoff[b + 1];
    int lo = b << BSH;
    int hi = lo + (1 << BSH); if (hi > n_nodes) hi = n_nodes;
    int nn = hi - lo;
    int ne = e1 - e0;

    for (int i = tid; i < 512; i += BLOCK) deg[i] = 0;
    __syncthreads();
    for (int i = e0 + tid; i < e1; i += BLOCK)
        atomicAdd(&deg[pairs[i].y - lo], 1);
    __syncthreads();

    int d0 = deg[2 * tid], d1 = deg[2 * tid + 1];
    int s = d0 + d1;
    int lane = tid & 63, w = tid >> 6;
    int v = s;
#pragma unroll
    for (int off = 1; off < 64; off <<= 1) {
        int u = __shfl_up(v, off);
        if (lane >= off) v += u;
    }
    if (lane == 63) wps[w] = v;
    __syncthreads();
    int wb = 0;
    for (int k = 0; k < w; ++k) wb += wps[k];
    int excl = wb + v - s;
    lst[2 * tid] = excl;
    lst[2 * tid + 1] = excl + d0;
    cur[2 * tid] = 0;
    cur[2 * tid + 1] = 0;
    __syncthreads();

    for (int i = tid; i < nn; i += BLOCK) {
        start[lo + i] = e0 + lst[i];
        int d = deg[i];
        invdeg[lo + i] = 1.0f / (float)(d < 1 ? 1 : d);
    }

    if (ne <= CAP) {
        for (int i = e0 + tid; i < e1; i += BLOCK) {
            int2 pr = pairs[i];
            int dl = pr.y - lo;
            int sl = lst[dl] + atomicAdd(&cur[dl], 1);
            scsr[sl] = pr.x;
        }
        __syncthreads();
        for (int i = tid; i < ne; i += BLOCK) csr_src[e0 + i] = scsr[i];
    } else {
        for (int i = e0 + tid; i < e1; i += BLOCK) {
            int2 pr = pairs[i];
            int dl = pr.y - lo;
            int sl = lst[dl] + atomicAdd(&cur[dl], 1);
            csr_src[e0 + sl] = pr.x;
        }
    }
}

// ---------------- register-tiled projection: pre = h@Ws + b ; p = h@Wn ----------------
// K-chunked staging of BOTH x and W (LDS ~25KB -> 4+ blocks/CU).
template<int DIN, int DOUT>
__global__ __launch_bounds__(256, 4)
void proj_tiled(const float* __restrict__ h,
                const float* __restrict__ Ws,
                const float* __restrict__ Wn,
                const float* __restrict__ bias,
                float* __restrict__ pre,
                float* __restrict__ p,
                int n_nodes) {
    constexpr int OD  = 2 * DOUT;
    constexpr int OPT = 8;
    constexpr int OG  = OD / OPT;
    constexpr int NPT = 4;
    constexpr int NG  = 256 / OG;
    constexpr int NT  = NPT * NG;
    constexpr int KC  = 32;
    constexpr int NCH = DIN / KC;

    __shared__ float sW[KC][OD];        // one K-chunk of weights
    __shared__ float sx[NT][KC + 1];
    __shared__ float sb[DOUT];

    const int tid = threadIdx.x;
    if (tid < DOUT) sb[tid] = bias[tid];

    const int to = tid % OG;
    const int tn = tid / OG;
    const int o0 = to * OPT;
    const int node0 = blockIdx.x * NT;

    float acc[NPT][OPT];
#pragma unroll
    for (int n = 0; n < NPT; ++n)
#pragma unroll
        for (int o = 0; o < OPT; ++o) acc[n][o] = 0.f;

    constexpr int L4 = NT * KC / (256 * 4);
    for (int c = 0; c < NCH; ++c) {
        if (c > 0) __syncthreads();
        // stage x chunk (coalesced float4)
#pragma unroll
        for (int q = 0; q < L4; ++q) {
            int fq   = q * 256 + tid;
            int node = fq / (KC / 4);
            int kq   = fq % (KC / 4);
            float4 v = make_float4(0.f, 0.f, 0.f, 0.f);
            int gn = node0 + node;
            if (gn < n_nodes)
                v = *reinterpret_cast<const float4*>(h + (size_t)gn * DIN + c * KC + kq * 4);
            sx[node][kq * 4 + 0] = v.x;
            sx[node][kq * 4 + 1] = v.y;
            sx[node][kq * 4 + 2] = v.z;
            sx[node][kq * 4 + 3] = v.w;
        }
        // stage W chunk
#pragma unroll
        for (int i = tid; i < KC * OD; i += 256) {
            int k = i / OD, o = i % OD;
            int kk = c * KC + k;
            sW[k][o] = (o < DOUT) ? Ws[kk * DOUT + o] : Wn[kk * DOUT + (o - DOUT)];
        }
        __syncthreads();

#pragma unroll 8
        for (int k = 0; k < KC; ++k) {
            const float4 wa = *reinterpret_cast<const float4*>(&sW[k][o0]);
            const float4 wb = *reinterpret_cast<const float4*>(&sW[k][o0 + 4]);
            float xv[NPT];
#pragma unroll
            for (int n = 0; n < NPT; ++n) xv[n] = sx[tn * NPT + n][k];
#pragma unroll
            for (int n = 0; n < NPT; ++n) {
                acc[n][0] = fmaf(xv[n], wa.x, acc[n][0]);
                acc[n][1] = fmaf(xv[n], wa.y, acc[n][1]);
                acc[n][2] = fmaf(xv[n], wa.z, acc[n][2]);
                acc[n][3] = fmaf(xv[n], wa.w, acc[n][3]);
                acc[n][4] = fmaf(xv[n], wb.x, acc[n][4]);
                acc[n][5] = fmaf(xv[n], wb.y, acc[n][5]);
                acc[n][6] = fmaf(xv[n], wb.z, acc[n][6]);
                acc[n][7] = fmaf(xv[n], wb.w, acc[n][7]);
            }
        }
    }

    const bool self_half = (o0 < DOUT);
#pragma unroll
    for (int n = 0; n < NPT; ++n) {
        int node = node0 + tn * NPT + n;
        if (node >= n_nodes) continue;
        if (self_half) {
            float4 r0 = make_float4(acc[n][0] + sb[o0 + 0], acc[n][1] + sb[o0 + 1],
                                    acc[n][2] + sb[o0 + 2], acc[n][3] + sb[o0 + 3]);
            float4 r1 = make_float4(acc[n][4] + sb[o0 + 4], acc[n][5] + sb[o0 + 5],
                                    acc[n][6] + sb[o0 + 6], acc[n][7] + sb[o0 + 7]);
            *reinterpret_cast<float4*>(pre + (size_t)node * DOUT + o0)     = r0;
            *reinterpret_cast<float4*>(pre + (size_t)node * DOUT + o0 + 4) = r1;
        } else {
            int oo = o0 - DOUT;
            float4 r0 = make_float4(acc[n][0], acc[n][1], acc[n][2], acc[n][3]);
            float4 r1 = make_float4(acc[n][4], acc[n][5], acc[n][6], acc[n][7]);
            *reinterpret_cast<float4*>(p + (size_t)node * DOUT + oo)     = r0;
            *reinterpret_cast<float4*>(p + (size_t)node * DOUT + oo + 4) = r1;
        }
    }
}

// ---------------- float4 sub-group gather + finalize ----------------
template<int D, bool RELU>
__global__ void gather_kernel(const float* __restrict__ p,
                              const int* __restrict__ csr_src,
                              const int* __restrict__ start,
                              const float* __restrict__ pre,
                              const float* __restrict__ invdeg,
                              float* __restrict__ out,
                              int n_nodes) {
    constexpr int LPN = D / 4;
    constexpr int NPG = 64 / LPN;
    int wave = threadIdx.x >> 6;
    int lane = threadIdx.x & 63;
    int g = blockIdx.x * (blockDim.x >> 6) + wave;
    if (g >= n_nodes) return;
    int sub = lane / LPN;
    int fl  = lane % LPN;
    int s0 = start[g];
    int s1 = start[g + 1];
    const float4* __restrict__ p4 = reinterpret_cast<const float4*>(p);
    float4 a0 = make_float4(0.f, 0.f, 0.f, 0.f);
    float4 a1 = make_float4(0.f, 0.f, 0.f, 0.f);
    int j = s0 + sub;
    for (; j + NPG < s1; j += 2 * NPG) {
        int c0 = csr_src[j];
        int c1 = csr_src[j + NPG];
        float4 v0 = p4[c0 * LPN + fl];
        float4 v1 = p4[c1 * LPN + fl];
        a0.x += v0.x; a0.y += v0.y; a0.z += v0.z; a0.w += v0.w;
        a1.x += v1.x; a1.y += v1.y; a1.z += v1.z; a1.w += v1.w;
    }
    if (j < s1) {
        float4 v = p4[csr_src[j] * LPN + fl];
        a0.x += v.x; a0.y += v.y; a0.z += v.z; a0.w += v.w;
    }
    float4 a = make_float4(a0.x + a1.x, a0.y + a1.y, a0.z + a1.z, a0.w + a1.w);
#pragma unroll
    for (int off = 32; off >= LPN; off >>= 1) {
        a.x += __shfl_down(a.x, off);
        a.y += __shfl_down(a.y, off);
        a.z += __shfl_down(a.z, off);
        a.w += __shfl_down(a.w, off);
    }
    if (lane < LPN) {
        float id = invdeg[g];
        float4 pr = reinterpret_cast<const float4*>(pre)[g * LPN + fl];
        float4 r;
        r.x = pr.x + a.x * id;
        r.y = pr.y + a.y * id;
        r.z = pr.z + a.z * id;
        r.w = pr.w + a.w * id;
        if (RELU) {
            r.x = fmaxf(r.x, 0.f); r.y = fmaxf(r.y, 0.f);
            r.z = fmaxf(r.z, 0.f); r.w = fmaxf(r.w, 0.f);
        }
        reinterpret_cast<float4*>(out)[g * LPN + fl] = r;
    }
}

extern "C" void kernel_launch(void* const* d_in, const int* in_sizes, int n_in,
                              void* d_out, int out_size, void* d_ws, size_t ws_size,
                              hipStream_t stream) {
    const float* x        = (const float*)d_in[0];
    const int*   edge_src = (const int*)d_in[1];
    const int*   edge_dst = (const int*)d_in[2];
    const float* Ws1 = (const float*)d_in[3];
    const float* Wn1 = (const float*)d_in[4];
    const float* b1  = (const float*)d_in[5];
    const float* Ws2 = (const float*)d_in[6];
    const float* Wn2 = (const float*)d_in[7];
    const float* b2  = (const float*)d_in[8];
    const float* Ws3 = (const float*)d_in[9];
    const float* Wn3 = (const float*)d_in[10];
    const float* b3  = (const float*)d_in[11];
    float* out = (float*)d_out;

    const int IN = 128, HID = 32;
    const int n_nodes = in_sizes[0] / IN;
    const int n_edges = in_sizes[1];
    const int nbuk = (n_nodes + (1 << BSH) - 1) >> BSH;   // 196
    const int ch   = (n_edges + NBLK - 1) / NBLK;         // 6250

    char* wsb = (char*)d_ws;
    size_t off = 0;
    auto alloc = [&](size_t bytes) { char* r = wsb + off; off = (off + bytes + 255) & ~(size_t)255; return r; };
    int*   startp = (int*)alloc(((size_t)n_nodes + 1) * sizeof(int));
    float* invdeg = (float*)alloc((size_t)n_nodes * sizeof(float));
    int*   csr    = (int*)alloc((size_t)n_edges * sizeof(int));
    int*   hist   = (int*)alloc((size_t)nbuk * NBLK * sizeof(int));
    int*   buktot = (int*)alloc(256 * sizeof(int));
    int*   bukoff = (int*)alloc(257 * sizeof(int));
    float* B0     = (float*)alloc((size_t)n_nodes * HID * sizeof(float));  // pre
    float* B1     = (float*)alloc((size_t)n_nodes * HID * sizeof(float));  // p
    float* B3     = (float*)alloc((size_t)n_nodes * HID * sizeof(float));  // h
    int2*  pairs  = (int2*)B0;   // CSR build fully precedes proj1 on the stream

    const int gP12   = (n_nodes + 127) / 128;
    const int gP3    = (n_nodes + 255) / 256;
    const int gGat   = (n_nodes + 3) / 4;

    // ---- CSR build: hist -> hierarchical scan -> partition -> per-bucket build ----
    hist_kernel   <<<NBLK, BLOCK, 0, stream>>>(edge_dst, hist, n_edges, nbuk, ch);
    scanBlk_kernel<<<nbuk, BLOCK, 0, stream>>>(hist, buktot);
    scanBuk_kernel<<<1, BLOCK, 0, stream>>>(buktot, bukoff, nbuk, startp, n_nodes, n_edges);
    part_kernel   <<<NBLK, BLOCK, 0, stream>>>(edge_src, edge_dst, hist, bukoff, pairs, n_edges, nbuk, ch);
    build_kernel  <<<nbuk, BLOCK, 0, stream>>>(pairs, bukoff, startp, invdeg, csr, n_nodes);

    // ---- layer 1: 128 -> 32, relu ----
    proj_tiled<128, 32><<<gP12, BLOCK, 0, stream>>>(x, Ws1, Wn1, b1, B0, B1, n_nodes);
    gather_kernel<32, true><<<gGat, BLOCK, 0, stream>>>(B1, csr, startp, B0, invdeg, B3, n_nodes);

    // ---- layer 2: 32 -> 32, relu ----
    proj_tiled<32, 32><<<gP12, BLOCK, 0, stream>>>(B3, Ws2, Wn2, b2, B0, B1, n_nodes);
    gather_kernel<32, true><<<gGat, BLOCK, 0, stream>>>(B1, csr, startp, B0, invdeg, B3, n_nodes);

    // ---- layer 3: 32 -> 16, no relu ----
    proj_tiled<32, 16><<<gP3, BLOCK, 0, stream>>>(B3, Ws3, Wn3, b3, B0, B1, n_nodes);
    gather_kernel<16, false><<<gGat, BLOCK, 0, stream>>>(B1, csr, startp, B0, invdeg, out, n_nodes);
}

// Round 10
// 221.208 us; speedup vs baseline: 2.6908x; 1.0068x over previous
//
#include <hip/hip_runtime.h>

// GraphSAGE 3-layer (mean agg), N=100000, E=1600000, 128->32->32->16.
// Round 10: proj restructured — x read directly from global (8-lane broadcast
// per output-group, no LDS staging, no per-chunk barriers), W staged in LDS
// once. Round 9's proj was LDS-BW-bound (48B LDS per 64 FLOP > 128B/clk/CU
// budget); now 32B/64FLOP = balance point. CSR build + gathers unchanged.

#define BLOCK 256
#define NBLK 256            // blocks for hist/part passes
#define BSH 9               // 512 nodes per bucket
#define CAP 12288           // max edges per bucket staged in LDS

// ---------------- phase 1: per-(bucket,block) histogram of dst ----------------
__global__ void hist_kernel(const int* __restrict__ dst, int* __restrict__ hist,
                            int n_edges, int nbuk, int ch) {
    __shared__ int cnt[256];
    int tid = threadIdx.x;
    for (int i = tid; i < nbuk; i += BLOCK) cnt[i] = 0;
    __syncthreads();
    int e0 = blockIdx.x * ch;
    int e1 = e0 + ch; if (e1 > n_edges) e1 = n_edges;
    for (int e = e0 + tid; e < e1; e += BLOCK)
        atomicAdd(&cnt[dst[e] >> BSH], 1);
    __syncthreads();
    for (int i = tid; i < nbuk; i += BLOCK)
        hist[i * NBLK + blockIdx.x] = cnt[i];
}

// ---------------- phase 2a: per-bucket exclusive scan of its 256 block-counts ----------------
__global__ void scanBlk_kernel(int* __restrict__ hist, int* __restrict__ buktot) {
    int b = blockIdx.x;
    int tid = threadIdx.x;
    int orig = hist[b * NBLK + tid];
    int v = orig;
    int lane = tid & 63, w = tid >> 6;
#pragma unroll
    for (int off = 1; off < 64; off <<= 1) {
        int u = __shfl_up(v, off);
        if (lane >= off) v += u;
    }
    __shared__ int wps[4];
    if (lane == 63) wps[w] = v;
    __syncthreads();
    int wadd = 0;
    for (int k = 0; k < w; ++k) wadd += wps[k];
    int excl = v - orig + wadd;
    hist[b * NBLK + tid] = excl;
    if (tid == 255) buktot[b] = excl + orig;
}

// ---------------- phase 2b: exclusive scan of bucket totals (1 block) ----------------
__global__ void scanBuk_kernel(const int* __restrict__ buktot, int* __restrict__ bukoff,
                               int nbuk, int* __restrict__ startp, int n_nodes, int n_edges) {
    int tid = threadIdx.x;
    int orig = (tid < nbuk) ? buktot[tid] : 0;
    int v = orig;
    int lane = tid & 63, w = tid >> 6;
#pragma unroll
    for (int off = 1; off < 64; off <<= 1) {
        int u = __shfl_up(v, off);
        if (lane >= off) v += u;
    }
    __shared__ int wps[4];
    if (lane == 63) wps[w] = v;
    __syncthreads();
    int wadd = 0;
    for (int k = 0; k < w; ++k) wadd += wps[k];
    int excl = v - orig + wadd;
    if (tid < nbuk) bukoff[tid] = excl;
    if (tid == 0) { bukoff[nbuk] = n_edges; startp[n_nodes] = n_edges; }
}

// ---------------- phase 3: partition (src,dst) pairs bucket-contiguously ----------------
__global__ void part_kernel(const int* __restrict__ src, const int* __restrict__ dst,
                            const int* __restrict__ hist, const int* __restrict__ bukoff,
                            int2* __restrict__ pairs, int n_edges, int nbuk, int ch) {
    __shared__ int base[256];
    __shared__ int cnt[256];
    int tid = threadIdx.x;
    for (int i = tid; i < nbuk; i += BLOCK) {
        base[i] = hist[i * NBLK + blockIdx.x] + bukoff[i];
        cnt[i] = 0;
    }
    __syncthreads();
    int e0 = blockIdx.x * ch;
    int e1 = e0 + ch; if (e1 > n_edges) e1 = n_edges;
    for (int e = e0 + tid; e < e1; e += BLOCK) {
        int d = dst[e];
        int b = d >> BSH;
        int r = atomicAdd(&cnt[b], 1);
        pairs[base[b] + r] = make_int2(src[e], d);
    }
}

// ---------------- phase 4: per-bucket CSR build in LDS ----------------
__global__ void build_kernel(const int2* __restrict__ pairs, const int* __restrict__ bukoff,
                             int* __restrict__ start, float* __restrict__ invdeg,
                             int* __restrict__ csr_src, int n_nodes) {
    __shared__ int deg[512];
    __shared__ int lst[512];
    __shared__ int cur[512];
    __shared__ int wps[4];
    __shared__ int scsr[CAP];

    int b = blockIdx.x;
    int tid = threadIdx.x;
    int e0 = bukoff[b];
    int e1 = bukoff[b + 1];
    int lo = b << BSH;
    int hi = lo + (1 << BSH); if (hi > n_nodes) hi = n_nodes;
    int nn = hi - lo;
    int ne = e1 - e0;

    for (int i = tid; i < 512; i += BLOCK) deg[i] = 0;
    __syncthreads();
    for (int i = e0 + tid; i < e1; i += BLOCK)
        atomicAdd(&deg[pairs[i].y - lo], 1);
    __syncthreads();

    int d0 = deg[2 * tid], d1 = deg[2 * tid + 1];
    int s = d0 + d1;
    int lane = tid & 63, w = tid >> 6;
    int v = s;
#pragma unroll
    for (int off = 1; off < 64; off <<= 1) {
        int u = __shfl_up(v, off);
        if (lane >= off) v += u;
    }
    if (lane == 63) wps[w] = v;
    __syncthreads();
    int wb = 0;
    for (int k = 0; k < w; ++k) wb += wps[k];
    int excl = wb + v - s;
    lst[2 * tid] = excl;
    lst[2 * tid + 1] = excl + d0;
    cur[2 * tid] = 0;
    cur[2 * tid + 1] = 0;
    __syncthreads();

    for (int i = tid; i < nn; i += BLOCK) {
        start[lo + i] = e0 + lst[i];
        int d = deg[i];
        invdeg[lo + i] = 1.0f / (float)(d < 1 ? 1 : d);
    }

    if (ne <= CAP) {
        for (int i = e0 + tid; i < e1; i += BLOCK) {
            int2 pr = pairs[i];
            int dl = pr.y - lo;
            int sl = lst[dl] + atomicAdd(&cur[dl], 1);
            scsr[sl] = pr.x;
        }
        __syncthreads();
        for (int i = tid; i < ne; i += BLOCK) csr_src[e0 + i] = scsr[i];
    } else {
        for (int i = e0 + tid; i < e1; i += BLOCK) {
            int2 pr = pairs[i];
            int dl = pr.y - lo;
            int sl = lst[dl] + atomicAdd(&cur[dl], 1);
            csr_src[e0 + sl] = pr.x;
        }
    }
}

// ---------------- projection: pre = h@Ws + b ; p = h@Wn ----------------
// W staged in LDS once (one barrier). x loaded directly from global as float4
// (8 lanes of an output-group share the address -> broadcast fetch).
template<int DIN, int DOUT, int OPT>
__global__ __launch_bounds__(256, 4)
void proj_reg(const float* __restrict__ h,
              const float* __restrict__ Ws,
              const float* __restrict__ Wn,
              const float* __restrict__ bias,
              float* __restrict__ pre,
              float* __restrict__ p,
              int n_nodes) {
    constexpr int OD  = 2 * DOUT;
    constexpr int OG  = OD / OPT;       // output groups
    constexpr int NPT = 4;              // nodes per thread
    constexpr int NG  = 256 / OG;       // node groups
    constexpr int NT  = NPT * NG;       // node tile
    constexpr int NV  = OPT / 4;        // float4s of output per thread

    __shared__ float sW[DIN][OD];
    __shared__ float sb[DOUT];

    const int tid = threadIdx.x;
    for (int i = tid; i < DIN * OD; i += 256) {
        int k = i / OD, o = i % OD;
        sW[k][o] = (o < DOUT) ? Ws[k * DOUT + o] : Wn[k * DOUT + (o - DOUT)];
    }
    if (tid < DOUT) sb[tid] = bias[tid];
    __syncthreads();

    const int to = tid % OG;
    const int tn = tid / OG;
    const int o0 = to * OPT;
    const int node0 = blockIdx.x * NT + tn * NPT;

    const float4* __restrict__ xp[NPT];
#pragma unroll
    for (int n = 0; n < NPT; ++n) {
        int node = node0 + n;
        int safe = (node < n_nodes) ? node : (n_nodes - 1);
        xp[n] = reinterpret_cast<const float4*>(h + (size_t)safe * DIN);
    }

    float acc[NPT][OPT];
#pragma unroll
    for (int n = 0; n < NPT; ++n)
#pragma unroll
        for (int o = 0; o < OPT; ++o) acc[n][o] = 0.f;

#pragma unroll 2
    for (int k4 = 0; k4 < DIN / 4; ++k4) {
        float4 xv[NPT];
#pragma unroll
        for (int n = 0; n < NPT; ++n) xv[n] = xp[n][k4];
#pragma unroll
        for (int kk = 0; kk < 4; ++kk) {
            int k = 4 * k4 + kk;
            float4 w[NV];
#pragma unroll
            for (int v = 0; v < NV; ++v)
                w[v] = *reinterpret_cast<const float4*>(&sW[k][o0 + 4 * v]);
#pragma unroll
            for (int n = 0; n < NPT; ++n) {
                float xk = reinterpret_cast<const float*>(&xv[n])[kk];
#pragma unroll
                for (int v = 0; v < NV; ++v) {
                    acc[n][4 * v + 0] = fmaf(xk, w[v].x, acc[n][4 * v + 0]);
                    acc[n][4 * v + 1] = fmaf(xk, w[v].y, acc[n][4 * v + 1]);
                    acc[n][4 * v + 2] = fmaf(xk, w[v].z, acc[n][4 * v + 2]);
                    acc[n][4 * v + 3] = fmaf(xk, w[v].w, acc[n][4 * v + 3]);
                }
            }
        }
    }

    const bool self_half = (o0 < DOUT);
    const int oo = self_half ? o0 : (o0 - DOUT);
    float* __restrict__ dstbuf = self_half ? pre : p;
#pragma unroll
    for (int n = 0; n < NPT; ++n) {
        int node = node0 + n;
        if (node >= n_nodes) continue;
#pragma unroll
        for (int v = 0; v < NV; ++v) {
            float4 r;
            r.x = acc[n][4 * v + 0];
            r.y = acc[n][4 * v + 1];
            r.z = acc[n][4 * v + 2];
            r.w = acc[n][4 * v + 3];
            if (self_half) {
                r.x += sb[oo + 4 * v + 0];
                r.y += sb[oo + 4 * v + 1];
                r.z += sb[oo + 4 * v + 2];
                r.w += sb[oo + 4 * v + 3];
            }
            *reinterpret_cast<float4*>(dstbuf + (size_t)node * DOUT + oo + 4 * v) = r;
        }
    }
}

// ---------------- float4 sub-group gather + finalize ----------------
template<int D, bool RELU>
__global__ void gather_kernel(const float* __restrict__ p,
                              const int* __restrict__ csr_src,
                              const int* __restrict__ start,
                              const float* __restrict__ pre,
                              const float* __restrict__ invdeg,
                              float* __restrict__ out,
                              int n_nodes) {
    constexpr int LPN = D / 4;
    constexpr int NPG = 64 / LPN;
    int wave = threadIdx.x >> 6;
    int lane = threadIdx.x & 63;
    int g = blockIdx.x * (blockDim.x >> 6) + wave;
    if (g >= n_nodes) return;
    int sub = lane / LPN;
    int fl  = lane % LPN;
    int s0 = start[g];
    int s1 = start[g + 1];
    const float4* __restrict__ p4 = reinterpret_cast<const float4*>(p);
    float4 a0 = make_float4(0.f, 0.f, 0.f, 0.f);
    float4 a1 = make_float4(0.f, 0.f, 0.f, 0.f);
    int j = s0 + sub;
    for (; j + NPG < s1; j += 2 * NPG) {
        int c0 = csr_src[j];
        int c1 = csr_src[j + NPG];
        float4 v0 = p4[c0 * LPN + fl];
        float4 v1 = p4[c1 * LPN + fl];
        a0.x += v0.x; a0.y += v0.y; a0.z += v0.z; a0.w += v0.w;
        a1.x += v1.x; a1.y += v1.y; a1.z += v1.z; a1.w += v1.w;
    }
    if (j < s1) {
        float4 v = p4[csr_src[j] * LPN + fl];
        a0.x += v.x; a0.y += v.y; a0.z += v.z; a0.w += v.w;
    }
    float4 a = make_float4(a0.x + a1.x, a0.y + a1.y, a0.z + a1.z, a0.w + a1.w);
#pragma unroll
    for (int off = 32; off >= LPN; off >>= 1) {
        a.x += __shfl_down(a.x, off);
        a.y += __shfl_down(a.y, off);
        a.z += __shfl_down(a.z, off);
        a.w += __shfl_down(a.w, off);
    }
    if (lane < LPN) {
        float id = invdeg[g];
        float4 pr = reinterpret_cast<const float4*>(pre)[g * LPN + fl];
        float4 r;
        r.x = pr.x + a.x * id;
        r.y = pr.y + a.y * id;
        r.z = pr.z + a.z * id;
        r.w = pr.w + a.w * id;
        if (RELU) {
            r.x = fmaxf(r.x, 0.f); r.y = fmaxf(r.y, 0.f);
            r.z = fmaxf(r.z, 0.f); r.w = fmaxf(r.w, 0.f);
        }
        reinterpret_cast<float4*>(out)[g * LPN + fl] = r;
    }
}

extern "C" void kernel_launch(void* const* d_in, const int* in_sizes, int n_in,
                              void* d_out, int out_size, void* d_ws, size_t ws_size,
                              hipStream_t stream) {
    const float* x        = (const float*)d_in[0];
    const int*   edge_src = (const int*)d_in[1];
    const int*   edge_dst = (const int*)d_in[2];
    const float* Ws1 = (const float*)d_in[3];
    const float* Wn1 = (const float*)d_in[4];
    const float* b1  = (const float*)d_in[5];
    const float* Ws2 = (const float*)d_in[6];
    const float* Wn2 = (const float*)d_in[7];
    const float* b2  = (const float*)d_in[8];
    const float* Ws3 = (const float*)d_in[9];
    const float* Wn3 = (const float*)d_in[10];
    const float* b3  = (const float*)d_in[11];
    float* out = (float*)d_out;

    const int IN = 128, HID = 32;
    const int n_nodes = in_sizes[0] / IN;
    const int n_edges = in_sizes[1];
    const int nbuk = (n_nodes + (1 << BSH) - 1) >> BSH;   // 196
    const int ch   = (n_edges + NBLK - 1) / NBLK;         // 6250

    char* wsb = (char*)d_ws;
    size_t off = 0;
    auto alloc = [&](size_t bytes) { char* r = wsb + off; off = (off + bytes + 255) & ~(size_t)255; return r; };
    int*   startp = (int*)alloc(((size_t)n_nodes + 1) * sizeof(int));
    float* invdeg = (float*)alloc((size_t)n_nodes * sizeof(float));
    int*   csr    = (int*)alloc((size_t)n_edges * sizeof(int));
    int*   hist   = (int*)alloc((size_t)nbuk * NBLK * sizeof(int));
    int*   buktot = (int*)alloc(256 * sizeof(int));
    int*   bukoff = (int*)alloc(257 * sizeof(int));
    float* B0     = (float*)alloc((size_t)n_nodes * HID * sizeof(float));  // pre
    float* B1     = (float*)alloc((size_t)n_nodes * HID * sizeof(float));  // p
    float* B3     = (float*)alloc((size_t)n_nodes * HID * sizeof(float));  // h
    int2*  pairs  = (int2*)B0;   // CSR build fully precedes proj1 on the stream

    const int gP    = (n_nodes + 127) / 128;   // all proj layers use NT=128
    const int gGat  = (n_nodes + 3) / 4;

    // ---- CSR build: hist -> hierarchical scan -> partition -> per-bucket build ----
    hist_kernel   <<<NBLK, BLOCK, 0, stream>>>(edge_dst, hist, n_edges, nbuk, ch);
    scanBlk_kernel<<<nbuk, BLOCK, 0, stream>>>(hist, buktot);
    scanBuk_kernel<<<1, BLOCK, 0, stream>>>(buktot, bukoff, nbuk, startp, n_nodes, n_edges);
    part_kernel   <<<NBLK, BLOCK, 0, stream>>>(edge_src, edge_dst, hist, bukoff, pairs, n_edges, nbuk, ch);
    build_kernel  <<<nbuk, BLOCK, 0, stream>>>(pairs, bukoff, startp, invdeg, csr, n_nodes);

    // ---- layer 1: 128 -> 32, relu ----
    proj_reg<128, 32, 8><<<gP, BLOCK, 0, stream>>>(x, Ws1, Wn1, b1, B0, B1, n_nodes);
    gather_kernel<32, true><<<gGat, BLOCK, 0, stream>>>(B1, csr, startp, B0, invdeg, B3, n_nodes);

    // ---- layer 2: 32 -> 32, relu ----
    proj_reg<32, 32, 8><<<gP, BLOCK, 0, stream>>>(B3, Ws2, Wn2, b2, B0, B1, n_nodes);
    gather_kernel<32, true><<<gGat, BLOCK, 0, stream>>>(B1, csr, startp, B0, invdeg, B3, n_nodes);

    // ---- layer 3: 32 -> 16, no relu ----
    proj_reg<32, 16, 4><<<gP, BLOCK, 0, stream>>>(B3, Ws3, Wn3, b3, B0, B1, n_nodes);
    gather_kernel<16, false><<<gGat, BLOCK, 0, stream>>>(B1, csr, startp, B0, invdeg, out, n_nodes);
}